// Round 12
// baseline (138.172 us; speedup 1.0000x reference)
//
#include <hip/hip_runtime.h>
#include <math.h>

#define PI_F 3.14159265358979323846f

typedef _Float16 half2_t __attribute__((ext_vector_type(2)));

__device__ __forceinline__ unsigned packh2(float lo, float hi) {
  unsigned short l = __builtin_bit_cast(unsigned short, (_Float16)lo);
  unsigned short h = __builtin_bit_cast(unsigned short, (_Float16)hi);
  return (unsigned)l | ((unsigned)h << 16);
}

struct c2 { float x, y; };
__device__ __forceinline__ c2 cmul(c2 a, c2 b){ return c2{a.x*b.x - a.y*b.y, a.x*b.y + a.y*b.x}; }
__device__ __forceinline__ c2 cadd(c2 a, c2 b){ return c2{a.x+b.x, a.y+b.y}; }

__device__ __forceinline__ void rot2(c2 &a, c2 &b, c2 g00, c2 g01, c2 g10, c2 g11) {
  c2 na = cadd(cmul(g00,a), cmul(g01,b));
  c2 nb = cadd(cmul(g10,a), cmul(g11,b));
  a = na; b = nb;
}

__device__ __forceinline__ void mk_u3(float th, float ph, float la,
                                      c2 &g00, c2 &g01, c2 &g10, c2 &g11) {
  float ch = cosf(0.5f*th), sh = sinf(0.5f*th);
  float cl = cosf(la), sl = sinf(la);
  float cp = cosf(ph), sp = sinf(ph);
  float cpl = cp*cl - sp*sl, spl = sp*cl + cp*sl;
  g00 = c2{ch, 0.f};
  g01 = c2{-cl*sh, -sl*sh};
  g10 = c2{cp*sh, sp*sh};
  g11 = c2{cpl*ch, spl*ch};
}

template<int MA, int MB>
__device__ __forceinline__ void apply2q(c2 psi[16], const c2 M[16]) {
#pragma unroll
  for (int r = 0; r < 16; ++r) {
    if (r & (MA | MB)) continue;
    c2 a = psi[r], b = psi[r|MB], c = psi[r|MA], d = psi[r|MA|MB];
    psi[r]        = cadd(cadd(cmul(M[0],a),  cmul(M[1],b)),  cadd(cmul(M[2],c),  cmul(M[3],d)));
    psi[r|MB]     = cadd(cadd(cmul(M[4],a),  cmul(M[5],b)),  cadd(cmul(M[6],c),  cmul(M[7],d)));
    psi[r|MA]     = cadd(cadd(cmul(M[8],a),  cmul(M[9],b)),  cadd(cmul(M[10],c), cmul(M[11],d)));
    psi[r|MA|MB]  = cadd(cadd(cmul(M[12],a), cmul(M[13],b)), cadd(cmul(M[14],c), cmul(M[15],d)));
  }
}

// ---------------- K0: build A_w = Re(U^dag Z_w U), 4 x 16 x 16 ----------------
__global__ __launch_bounds__(256) void k_qmat(const float* __restrict__ qw_u3,
                                              const float* __restrict__ qw_ang,
                                              float* __restrict__ A) {
  __shared__ c2 SU[2][16];
  __shared__ float Ur[16*17], Ui[16*17];
  int t = threadIdx.x;
  if (t < 8) {
    int L = t >> 2, col = t & 3;
    c2 s[4];
#pragma unroll
    for (int i = 0; i < 4; ++i) s[i] = c2{(i==col)?1.f:0.f, 0.f};
    const float* u = qw_u3 + 12*L;
    const float* g = qw_ang + 3*L;
    c2 g00,g01,g10,g11;
    mk_u3(u[0],u[1],u[2], g00,g01,g10,g11);             // u3s[0] on a (mask 2)
    rot2(s[0],s[2], g00,g01,g10,g11); rot2(s[1],s[3], g00,g01,g10,g11);
    mk_u3(u[3],u[4],u[5], g00,g01,g10,g11);             // u3s[1] on b (mask 1)
    rot2(s[0],s[1], g00,g01,g10,g11); rot2(s[2],s[3], g00,g01,g10,g11);
    { c2 tmp = s[2]; s[2] = s[3]; s[3] = tmp; }          // CNOT a->b
    { float c = cosf(0.5f*g[0]), sn = sinf(0.5f*g[0]);
      c2 r00{c,0.f}, r01{-sn,0.f}, r10{sn,0.f}, r11{c,0.f};
      rot2(s[0],s[2], r00,r01,r10,r11); rot2(s[1],s[3], r00,r01,r10,r11); } // RY on a
    { float c = cosf(0.5f*g[1]), sn = sinf(0.5f*g[1]);
      c2 e0{c,-sn}, e1{c,sn};
      s[0]=cmul(s[0],e0); s[1]=cmul(s[1],e1); s[2]=cmul(s[2],e0); s[3]=cmul(s[3],e1); } // RZ on b
    { c2 tmp = s[1]; s[1] = s[3]; s[3] = tmp; }          // CNOT b->a
    { float c = cosf(0.5f*g[2]), sn = sinf(0.5f*g[2]);
      c2 r00{c,0.f}, r01{-sn,0.f}, r10{sn,0.f}, r11{c,0.f};
      rot2(s[0],s[2], r00,r01,r10,r11); rot2(s[1],s[3], r00,r01,r10,r11); } // RY on a
    { c2 tmp = s[2]; s[2] = s[3]; s[3] = tmp; }          // CNOT a->b
    mk_u3(u[6],u[7],u[8], g00,g01,g10,g11);             // u3s[2] on a
    rot2(s[0],s[2], g00,g01,g10,g11); rot2(s[1],s[3], g00,g01,g10,g11);
    mk_u3(u[9],u[10],u[11], g00,g01,g10,g11);           // u3s[3] on b
    rot2(s[0],s[1], g00,g01,g10,g11); rot2(s[2],s[3], g00,g01,g10,g11);
#pragma unroll
    for (int k = 0; k < 4; ++k) SU[L][k*4 + col] = s[k];
  }
  __syncthreads();
  if (t < 16) {
    c2 psi[16];
#pragma unroll
    for (int i = 0; i < 16; ++i) psi[i] = c2{(i==t)?1.f:0.f, 0.f};
#pragma unroll
    for (int l = 0; l < 2; ++l) {
      c2 M[16];
#pragma unroll
      for (int k = 0; k < 16; ++k) M[k] = SU[l][k];
      apply2q<8,4>(psi, M);   // pair (0,1)
      apply2q<4,2>(psi, M);   // pair (1,2)
      apply2q<2,1>(psi, M);   // pair (2,3)
      apply2q<1,8>(psi, M);   // pair (3,0)
    }
#pragma unroll
    for (int k = 0; k < 16; ++k) { Ur[k*17+t] = psi[k].x; Ui[k*17+t] = psi[k].y; }
  }
  __syncthreads();
  {
    int i = t >> 4, j = t & 15;
    float a0=0.f,a1=0.f,a2=0.f,a3=0.f;
#pragma unroll
    for (int k = 0; k < 16; ++k) {
      float pr = Ur[k*17+i]*Ur[k*17+j] + Ui[k*17+i]*Ui[k*17+j];
      a0 += ((k>>3)&1) ? -pr : pr;
      a1 += ((k>>2)&1) ? -pr : pr;
      a2 += ((k>>1)&1) ? -pr : pr;
      a3 += ( k     &1) ? -pr : pr;
    }
    A[0*256 + t] = a0; A[1*256 + t] = a1; A[2*256 + t] = a2; A[3*256 + t] = a3;
  }
}

// ------- Ktrans: FC transposes + conv2 f16 pack + conv1 f16 pack (13 pairs + w26 + bias) -------
__global__ __launch_bounds__(256) void k_trans(const float* __restrict__ w1a, const float* __restrict__ w1b,
                                               const float* __restrict__ w2a, const float* __restrict__ w2b,
                                               const float* __restrict__ c2w,
                                               const float* __restrict__ c1w, const float* __restrict__ c1b,
                                               float* __restrict__ wt) {
  int id = blockIdx.x*256 + threadIdx.x;
  if (id < 16384) { int j = id >> 6, o = id & 63;  wt[id] = w1a[o*256 + j]; return; }
  int id1 = id - 16384;
  if (id1 < 8192)  { int j = id1 >> 7, o = id1 & 127; wt[16384 + id1] = w1b[o*64 + j]; return; }
  int id2 = id1 - 8192;
  if (id2 < 8192)  { int j = id2 >> 6, o = id2 & 63;  wt[24576 + id2] = w2a[o*128 + j]; return; }
  int id3 = id2 - 8192;
  if (id3 < 640)   { int j = id3 / 10, o = id3 % 10;  wt[32768 + id3] = w2b[o*64 + j]; return; }
  int id4 = id3 - 640;
  if (id4 < 4608) {
    int p = id4 / 144, rr = id4 - p*144;
    int oc = rr / 9, k = rr - oc*9;
    float lo = c2w[oc*576 + p*9 + k];
    float hi = c2w[oc*576 + (p+32)*9 + k];
    ((unsigned*)wt)[33408 + id4] = packh2(lo, hi);
    return;
  }
  int id5 = id4 - 4608;
  if (id5 < 1024) {
    int oc = id5 >> 4, s = id5 & 15;
    unsigned v;
    if (s < 13)      v = packh2(c1w[oc*27 + 2*s], c1w[oc*27 + 2*s + 1]);
    else if (s == 13) v = __builtin_bit_cast(unsigned, c1w[oc*27 + 26]);
    else if (s == 14) v = __builtin_bit_cast(unsigned, c1b[oc]);
    else             v = 0u;
    ((unsigned*)wt)[38016 + id5] = v;
  }
}

// ---- K1: conv1(3->64)+relu+pool, v3: f16 fdot2 (13 pairs + 1 fp32 leftover). ----
// Block (b, oh): pairs oh*16..oh*16+15. Windows packed once/thread, reused 16x.
__global__ __launch_bounds__(256) void k_conv1(const float* __restrict__ x,
                                               const unsigned* __restrict__ w1p,
                                               unsigned* __restrict__ h1p) {
  __shared__ float xs[3*32*32];
  int bid = blockIdx.x, b = bid >> 1, oh = bid & 1, tid = threadIdx.x;
  const float4* xsrc = (const float4*)(x + (size_t)b*3072);
  float4* xd = (float4*)xs;
#pragma unroll
  for (int k = 0; k < 3; ++k) xd[tid + k*256] = xsrc[tid + k*256];
  __syncthreads();
  int y = tid >> 4, xo = tid & 15;
  int y2 = y*2, x2 = xo*2;
  float in[3][4][4];
#pragma unroll
  for (int c = 0; c < 3; ++c)
#pragma unroll
    for (int ky = 0; ky < 4; ++ky) {
      int iy = y2 + ky - 1;
      bool vy = ((unsigned)iy < 32u);
      int iyc = vy ? iy : 0;
#pragma unroll
      for (int kx = 0; kx < 4; ++kx) {
        int ix = x2 + kx - 1;
        bool v = vy && ((unsigned)ix < 32u);
        int ixc = ((unsigned)ix < 32u) ? ix : 0;
        float val = xs[c*1024 + iyc*32 + ixc];
        in[c][ky][kx] = v ? val : 0.f;
      }
    }
  // pack the 4 conv-position windows: 13 half2 pairs + 1 fp32 leftover each
  half2_t pk[4][13];
  float l26[4];
#pragma unroll
  for (int pos = 0; pos < 4; ++pos) {
    int dy = pos >> 1, dx = pos & 1;
#pragma unroll
    for (int i = 0; i < 13; ++i) {
      int e0 = 2*i, e1 = 2*i + 1;
      float v0 = in[e0/9][(e0%9)/3 + dy][e0%3 + dx];
      float v1 = in[e1/9][(e1%9)/3 + dy][e1%3 + dx];
      pk[pos][i] = __builtin_bit_cast(half2_t, packh2(v0, v1));
    }
    l26[pos] = in[2][2+dy][2+dx];
  }
  unsigned* outp = h1p + (size_t)b*8192 + tid;
  int p0 = oh*16;
  for (int pi = 0; pi < 16; ++pi) {
    int p = p0 + pi;
    const unsigned* wa = w1p + p*16;        // wave-uniform -> s_load
    const unsigned* wb = w1p + (p+32)*16;
    float ba = __builtin_bit_cast(float, wa[14]);
    float bb = __builtin_bit_cast(float, wb[14]);
    float A0=ba, A1=ba, A2=ba, A3=ba;
    float C0=bb, C1=bb, C2=bb, C3=bb;
#pragma unroll
    for (int i = 0; i < 13; ++i) {
      half2_t wha = __builtin_bit_cast(half2_t, wa[i]);
      half2_t whb = __builtin_bit_cast(half2_t, wb[i]);
      A0 = __builtin_amdgcn_fdot2(pk[0][i], wha, A0, false);
      A1 = __builtin_amdgcn_fdot2(pk[1][i], wha, A1, false);
      A2 = __builtin_amdgcn_fdot2(pk[2][i], wha, A2, false);
      A3 = __builtin_amdgcn_fdot2(pk[3][i], wha, A3, false);
      C0 = __builtin_amdgcn_fdot2(pk[0][i], whb, C0, false);
      C1 = __builtin_amdgcn_fdot2(pk[1][i], whb, C1, false);
      C2 = __builtin_amdgcn_fdot2(pk[2][i], whb, C2, false);
      C3 = __builtin_amdgcn_fdot2(pk[3][i], whb, C3, false);
    }
    float w26a = __builtin_bit_cast(float, wa[13]);
    float w26b = __builtin_bit_cast(float, wb[13]);
    A0 = fmaf(w26a, l26[0], A0); A1 = fmaf(w26a, l26[1], A1);
    A2 = fmaf(w26a, l26[2], A2); A3 = fmaf(w26a, l26[3], A3);
    C0 = fmaf(w26b, l26[0], C0); C1 = fmaf(w26b, l26[1], C1);
    C2 = fmaf(w26b, l26[2], C2); C3 = fmaf(w26b, l26[3], C3);
    float ma = fmaxf(fmaxf(fmaxf(A0,A1), fmaxf(A2,A3)), 0.f);
    float mb = fmaxf(fmaxf(fmaxf(C0,C1), fmaxf(C2,C3)), 0.f);
    outp[p*256] = packh2(ma, mb);
  }
}

// ---- K2: conv2(64->16)+relu+pool, v8: full-image positions x 16 oc/thread, ----
// 2 chunks of 16 pairs with register prefetch. LDS [16 p][18 rows][24 u32] =
// 27648 B -> 5 blocks/CU. Data cols at index 4+c (guards 0..3 / 20..23 zero):
// uint4 staging writes 16B-aligned, quad-start banks uniform over 8 bank-groups
// -> minimal-cycle writes. Reads: bank = 24r + x + C, lanes 4r x 16x -> every
// bank exactly 2 lanes, conflict-free. Same accumulation order as v6/v7 ->
// bit-identical h2.
__global__ __launch_bounds__(256) void k_conv2(const unsigned* __restrict__ h1p,
                                               const unsigned* __restrict__ w2p,
                                               const float* __restrict__ bias, float* __restrict__ h2) {
  __shared__ unsigned hsp[16*18*24];   // 6912 u32 = 27648 B
  int b = blockIdx.x, t = threadIdx.x;
  {
    uint4 z = make_uint4(0u,0u,0u,0u);
    uint4* hz = (uint4*)hsp;
    for (int i = t; i < 1728; i += 256) hz[i] = z;
  }
  __syncthreads();
  const uint4* src = (const uint4*)(h1p + (size_t)b*8192);   // [32 p][16 rows][4 uint4]
  uint4* dst4 = (uint4*)hsp;
  // stage chunk 0 (p = 0..15): dst uint4 index = p*108 + (r16+1)*6 + 1 + c4
#pragma unroll
  for (int k = 0; k < 4; ++k) {
    int idx = t + k*256;               // 0..1023
    int p = idx >> 6, rem = idx & 63;
    int r16 = rem >> 2, c4 = rem & 3;
    dst4[p*108 + (r16+1)*6 + 1 + c4] = src[p*64 + r16*4 + c4];
  }
  // prefetch chunk 1 into registers (issued before barrier; consumed after compute)
  uint4 pre[4];
#pragma unroll
  for (int k = 0; k < 4; ++k) pre[k] = src[1024 + t + k*256];
  __syncthreads();
  int y = t >> 4, x = t & 15;
  float acc[16];
#pragma unroll
  for (int o = 0; o < 16; ++o) acc[o] = bias[o];
#pragma unroll 2
  for (int p = 0; p < 16; ++p) {
    unsigned in9[9];
#pragma unroll
    for (int dy = 0; dy < 3; ++dy)
#pragma unroll
      for (int kx = 0; kx < 3; ++kx)
        in9[dy*3+kx] = hsp[p*432 + (y+dy)*24 + 3 + x + kx];
    const unsigned* wp = w2p + p*144;  // wave-uniform -> s_load
#pragma unroll
    for (int o = 0; o < 16; ++o)
#pragma unroll
      for (int k9 = 0; k9 < 9; ++k9)
        acc[o] = __builtin_amdgcn_fdot2(__builtin_bit_cast(half2_t, in9[k9]),
                                        __builtin_bit_cast(half2_t, wp[o*9+k9]),
                                        acc[o], false);
  }
  __syncthreads();                     // chunk-0 reads done
#pragma unroll
  for (int k = 0; k < 4; ++k) {
    int idx = t + k*256;
    int p = idx >> 6, rem = idx & 63;
    int r16 = rem >> 2, c4 = rem & 3;
    dst4[p*108 + (r16+1)*6 + 1 + c4] = pre[k];
  }
  __syncthreads();                     // chunk-1 staged
#pragma unroll 2
  for (int p = 0; p < 16; ++p) {
    unsigned in9[9];
#pragma unroll
    for (int dy = 0; dy < 3; ++dy)
#pragma unroll
      for (int kx = 0; kx < 3; ++kx)
        in9[dy*3+kx] = hsp[p*432 + (y+dy)*24 + 3 + x + kx];
    const unsigned* wp = w2p + (16 + p)*144;
#pragma unroll
    for (int o = 0; o < 16; ++o)
#pragma unroll
      for (int k9 = 0; k9 < 9; ++k9)
        acc[o] = __builtin_amdgcn_fdot2(__builtin_bit_cast(half2_t, in9[k9]),
                                        __builtin_bit_cast(half2_t, wp[o*9+k9]),
                                        acc[o], false);
  }
  // 2x2 maxpool: x^1 via lane^1, y row bit0 via lane^16; relu + write
  int r = (t >> 4) & 3;
  bool writer = ((r & 1) == 0) && ((x & 1) == 0);
  int py = y >> 1, px = x >> 1;
  float* outb = h2 + (size_t)b*1024;
#pragma unroll
  for (int o = 0; o < 16; ++o) {
    float m = fmaxf(acc[o], __shfl_xor(acc[o], 1, 64));
    m = fmaxf(m, __shfl_xor(m, 16, 64));
    if (writer) outb[o*64 + py*8 + px] = fmaxf(m, 0.f);
  }
}

// ---- K3: conv3(16->4)+leaky+sigmoid*pi -> quantum quadratic forms (fused) ----
__global__ __launch_bounds__(256) void k_conv3q(const float* __restrict__ h2, const float* __restrict__ w,
                                                const float* __restrict__ bias, const float* __restrict__ Ag,
                                                float* __restrict__ q) {
  __shared__ float S[4*1600 + 1024];
  float* h3s = S;                      // 4 imgs x [16][10][10] zero-padded
  float* As  = S + 6400;               // [4][256]
  int b4 = blockIdx.x*4, t = threadIdx.x;
#pragma unroll
  for (int k = 0; k < 4; ++k) As[t + k*256] = Ag[t + k*256];
  for (int i = t; i < 6400; i += 256) h3s[i] = 0.f;
  __syncthreads();
  int img = t >> 6, lane = t & 63;
  const float4* src = (const float4*)(h2 + (size_t)(b4+img)*1024);
#pragma unroll
  for (int k = 0; k < 4; ++k) {
    float4 v = src[lane + k*64];
    int e = 4*(lane + k*64);
    int ic = e >> 6, iy = (e >> 3) & 7, ix = e & 7;
    float* d = &h3s[img*1600 + ic*100 + (iy+1)*10 + ix + 1];
    d[0]=v.x; d[1]=v.y; d[2]=v.z; d[3]=v.w;
  }
  __syncthreads();
  int y = lane >> 3, xo = lane & 7;
  float acc[4];
#pragma unroll
  for (int o = 0; o < 4; ++o) acc[o] = bias[o];
  for (int ic = 0; ic < 16; ++ic) {
    float in[3][3];
#pragma unroll
    for (int ky = 0; ky < 3; ++ky)
#pragma unroll
      for (int kx = 0; kx < 3; ++kx)
        in[ky][kx] = h3s[img*1600 + ic*100 + (y+ky)*10 + (xo+kx)];
#pragma unroll
    for (int o = 0; o < 4; ++o) {
      const float* wp = w + (o*16 + ic)*9;
#pragma unroll
      for (int ky = 0; ky < 3; ++ky)
#pragma unroll
        for (int kx = 0; kx < 3; ++kx)
          acc[o] = fmaf(wp[ky*3+kx], in[ky][kx], acc[o]);
    }
  }
  float v0[2], v1[2], v2[2], v3[2];
#pragma unroll
  for (int o = 0; o < 4; ++o) {
    float v = acc[o];
    float l = v > 0.f ? v : 0.01f*v;
    float sg = 1.f/(1.f + expf(-l));
    float sv, cv;
    __sincosf(sg * (0.5f*PI_F), &sv, &cv);
    float* dst = (o==0)?v0:(o==1)?v1:(o==2)?v2:v3;
    dst[0] = cv; dst[1] = sv;
  }
  float pv[16];
#pragma unroll
  for (int i = 0; i < 16; ++i)
    pv[i] = v0[(i>>3)&1] * v1[(i>>2)&1] * v2[(i>>1)&1] * v3[i&1];
  float ev[4];
#pragma unroll
  for (int w4 = 0; w4 < 4; ++w4) {
    const float4* Aw = (const float4*)(As + w4*256);
    float a = 0.f;
#pragma unroll
    for (int i = 0; i < 16; ++i) {
      float d = 0.f;
#pragma unroll
      for (int j4 = 0; j4 < 4; ++j4) {
        float4 av = Aw[i*4 + j4];
        d = fmaf(av.x, pv[j4*4+0], d);
        d = fmaf(av.y, pv[j4*4+1], d);
        d = fmaf(av.z, pv[j4*4+2], d);
        d = fmaf(av.w, pv[j4*4+3], d);
      }
      a = fmaf(pv[i], d, a);
    }
    ev[w4] = a;
  }
  size_t p = (size_t)(b4+img)*64 + lane;
  ((float4*)q)[p] = make_float4(ev[0], ev[1], ev[2], ev[3]);
}

// ---------------- K5: fused FC chain, one wave per batch row ----------------
__global__ __launch_bounds__(256) void k_fc(const float* __restrict__ q, const float* __restrict__ wt,
                                            const float* __restrict__ b1a, const float* __restrict__ b1b,
                                            const float* __restrict__ b2a, const float* __restrict__ b2b,
                                            float* __restrict__ out) {
  __shared__ float sh[4][512];
  int tid = threadIdx.x, wv = tid >> 6, lane = tid & 63;
  int row = blockIdx.x*4 + wv;
  float* S = sh[wv];
  const float4* qr = (const float4*)(q + (size_t)row*256);
  ((float4*)S)[lane] = qr[lane];
  __syncthreads();
  const float* WT1a = wt;
  const float* WT1b = wt + 16384;
  const float* WT2a = wt + 24576;
  const float* WT2b = wt + 32768;
  float acc = b1a[lane];
  for (int j = 0; j < 256; ++j) acc = fmaf(WT1a[j*64+lane], S[j], acc);
  float h = fmaxf(acc, 0.f);
  __syncthreads();
  S[256+lane] = h;
  __syncthreads();
  float a0 = b1b[lane], a1 = b1b[64+lane];
  for (int j = 0; j < 64; ++j) {
    float sj = S[256+j];
    a0 = fmaf(WT1b[j*128+lane],    sj, a0);
    a1 = fmaf(WT1b[j*128+64+lane], sj, a1);
  }
  __syncthreads();
  S[320+lane] = a0; S[384+lane] = a1;
  __syncthreads();
  float c2a = b2a[lane];
  for (int j = 0; j < 128; ++j) c2a = fmaf(WT2a[j*64+lane], S[320+j], c2a);
  float h2v = fmaxf(c2a, 0.f);
  __syncthreads();
  S[448+lane] = h2v;
  __syncthreads();
  if (lane < 10) {
    float o = b2b[lane];
    for (int j = 0; j < 64; ++j) o = fmaf(WT2b[j*10+lane], S[448+j], o);
    out[(size_t)row*10 + lane] = o;
  }
}

extern "C" void kernel_launch(void* const* d_in, const int* in_sizes, int n_in,
                              void* d_out, int out_size, void* d_ws, size_t ws_size,
                              hipStream_t stream) {
  const float* x       = (const float*)d_in[0];
  const float* conv1_w = (const float*)d_in[1];
  const float* conv1_b = (const float*)d_in[2];
  const float* conv2_w = (const float*)d_in[3];
  const float* conv2_b = (const float*)d_in[4];
  const float* conv3_w = (const float*)d_in[5];
  const float* conv3_b = (const float*)d_in[6];
  const float* qw_u3   = (const float*)d_in[7];
  const float* qw_ang  = (const float*)d_in[8];
  const float* fc1a_w  = (const float*)d_in[9];
  const float* fc1a_b  = (const float*)d_in[10];
  const float* fc1b_w  = (const float*)d_in[11];
  const float* fc1b_b  = (const float*)d_in[12];
  const float* fc2a_w  = (const float*)d_in[13];
  const float* fc2a_b  = (const float*)d_in[14];
  const float* fc2b_w  = (const float*)d_in[15];
  const float* fc2b_b  = (const float*)d_in[16];
  float* out = (float*)d_out;

  float* ws  = (float*)d_ws;
  float* A   = ws;                      // 1024 floats
  float* WT  = ws + 1024;               // fc transposes (33408 f32) + conv2 pk (4608 u32) + conv1 pk (1024 u32)
  const unsigned* W2P = (const unsigned*)WT + 33408;
  const unsigned* W1P = (const unsigned*)WT + 38016;
  float* q   = ws + 43648;              // 262144 floats (1024x256)
  unsigned* h1p = (unsigned*)(ws + 305792);  // 8388608 u32 (1024 x 32pair x 16 x 16)
  float* h2  = ws + 17083008;           // 1048576 floats  (1024x16x8x8)

  k_qmat  <<<1,    256, 0, stream>>>(qw_u3, qw_ang, A);
  k_trans <<<167,  256, 0, stream>>>(fc1a_w, fc1b_w, fc2a_w, fc2b_w, conv2_w, conv1_w, conv1_b, WT);
  k_conv1 <<<2048, 256, 0, stream>>>(x, W1P, h1p);
  k_conv2 <<<1024, 256, 0, stream>>>(h1p, W2P, conv2_b, h2);
  k_conv3q<<<256,  256, 0, stream>>>(h2, conv3_w, conv3_b, A, q);
  k_fc    <<<256,  256, 0, stream>>>(q, WT, fc1a_b, fc1b_b, fc2a_b, fc2b_b, out);
}

// Round 13
// 124.981 us; speedup vs baseline: 1.1055x; 1.1055x over previous
//
#include <hip/hip_runtime.h>
#include <math.h>

#define PI_F 3.14159265358979323846f

typedef _Float16 half2_t __attribute__((ext_vector_type(2)));

__device__ __forceinline__ unsigned packh2(float lo, float hi) {
  unsigned short l = __builtin_bit_cast(unsigned short, (_Float16)lo);
  unsigned short h = __builtin_bit_cast(unsigned short, (_Float16)hi);
  return (unsigned)l | ((unsigned)h << 16);
}

struct c2 { float x, y; };
__device__ __forceinline__ c2 cmul(c2 a, c2 b){ return c2{a.x*b.x - a.y*b.y, a.x*b.y + a.y*b.x}; }
__device__ __forceinline__ c2 cadd(c2 a, c2 b){ return c2{a.x+b.x, a.y+b.y}; }

__device__ __forceinline__ void rot2(c2 &a, c2 &b, c2 g00, c2 g01, c2 g10, c2 g11) {
  c2 na = cadd(cmul(g00,a), cmul(g01,b));
  c2 nb = cadd(cmul(g10,a), cmul(g11,b));
  a = na; b = nb;
}

__device__ __forceinline__ void mk_u3(float th, float ph, float la,
                                      c2 &g00, c2 &g01, c2 &g10, c2 &g11) {
  float ch = cosf(0.5f*th), sh = sinf(0.5f*th);
  float cl = cosf(la), sl = sinf(la);
  float cp = cosf(ph), sp = sinf(ph);
  float cpl = cp*cl - sp*sl, spl = sp*cl + cp*sl;
  g00 = c2{ch, 0.f};
  g01 = c2{-cl*sh, -sl*sh};
  g10 = c2{cp*sh, sp*sh};
  g11 = c2{cpl*ch, spl*ch};
}

template<int MA, int MB>
__device__ __forceinline__ void apply2q(c2 psi[16], const c2 M[16]) {
#pragma unroll
  for (int r = 0; r < 16; ++r) {
    if (r & (MA | MB)) continue;
    c2 a = psi[r], b = psi[r|MB], c = psi[r|MA], d = psi[r|MA|MB];
    psi[r]        = cadd(cadd(cmul(M[0],a),  cmul(M[1],b)),  cadd(cmul(M[2],c),  cmul(M[3],d)));
    psi[r|MB]     = cadd(cadd(cmul(M[4],a),  cmul(M[5],b)),  cadd(cmul(M[6],c),  cmul(M[7],d)));
    psi[r|MA]     = cadd(cadd(cmul(M[8],a),  cmul(M[9],b)),  cadd(cmul(M[10],c), cmul(M[11],d)));
    psi[r|MA|MB]  = cadd(cadd(cmul(M[12],a), cmul(M[13],b)), cadd(cmul(M[14],c), cmul(M[15],d)));
  }
}

// ---------------- K0: build A_w = Re(U^dag Z_w U), 4 x 16 x 16 ----------------
__global__ __launch_bounds__(256) void k_qmat(const float* __restrict__ qw_u3,
                                              const float* __restrict__ qw_ang,
                                              float* __restrict__ A) {
  __shared__ c2 SU[2][16];
  __shared__ float Ur[16*17], Ui[16*17];
  int t = threadIdx.x;
  if (t < 8) {
    int L = t >> 2, col = t & 3;
    c2 s[4];
#pragma unroll
    for (int i = 0; i < 4; ++i) s[i] = c2{(i==col)?1.f:0.f, 0.f};
    const float* u = qw_u3 + 12*L;
    const float* g = qw_ang + 3*L;
    c2 g00,g01,g10,g11;
    mk_u3(u[0],u[1],u[2], g00,g01,g10,g11);             // u3s[0] on a (mask 2)
    rot2(s[0],s[2], g00,g01,g10,g11); rot2(s[1],s[3], g00,g01,g10,g11);
    mk_u3(u[3],u[4],u[5], g00,g01,g10,g11);             // u3s[1] on b (mask 1)
    rot2(s[0],s[1], g00,g01,g10,g11); rot2(s[2],s[3], g00,g01,g10,g11);
    { c2 tmp = s[2]; s[2] = s[3]; s[3] = tmp; }          // CNOT a->b
    { float c = cosf(0.5f*g[0]), sn = sinf(0.5f*g[0]);
      c2 r00{c,0.f}, r01{-sn,0.f}, r10{sn,0.f}, r11{c,0.f};
      rot2(s[0],s[2], r00,r01,r10,r11); rot2(s[1],s[3], r00,r01,r10,r11); } // RY on a
    { float c = cosf(0.5f*g[1]), sn = sinf(0.5f*g[1]);
      c2 e0{c,-sn}, e1{c,sn};
      s[0]=cmul(s[0],e0); s[1]=cmul(s[1],e1); s[2]=cmul(s[2],e0); s[3]=cmul(s[3],e1); } // RZ on b
    { c2 tmp = s[1]; s[1] = s[3]; s[3] = tmp; }          // CNOT b->a
    { float c = cosf(0.5f*g[2]), sn = sinf(0.5f*g[2]);
      c2 r00{c,0.f}, r01{-sn,0.f}, r10{sn,0.f}, r11{c,0.f};
      rot2(s[0],s[2], r00,r01,r10,r11); rot2(s[1],s[3], r00,r01,r10,r11); } // RY on a
    { c2 tmp = s[2]; s[2] = s[3]; s[3] = tmp; }          // CNOT a->b
    mk_u3(u[6],u[7],u[8], g00,g01,g10,g11);             // u3s[2] on a
    rot2(s[0],s[2], g00,g01,g10,g11); rot2(s[1],s[3], g00,g01,g10,g11);
    mk_u3(u[9],u[10],u[11], g00,g01,g10,g11);           // u3s[3] on b
    rot2(s[0],s[1], g00,g01,g10,g11); rot2(s[2],s[3], g00,g01,g10,g11);
#pragma unroll
    for (int k = 0; k < 4; ++k) SU[L][k*4 + col] = s[k];
  }
  __syncthreads();
  if (t < 16) {
    c2 psi[16];
#pragma unroll
    for (int i = 0; i < 16; ++i) psi[i] = c2{(i==t)?1.f:0.f, 0.f};
#pragma unroll
    for (int l = 0; l < 2; ++l) {
      c2 M[16];
#pragma unroll
      for (int k = 0; k < 16; ++k) M[k] = SU[l][k];
      apply2q<8,4>(psi, M);   // pair (0,1)
      apply2q<4,2>(psi, M);   // pair (1,2)
      apply2q<2,1>(psi, M);   // pair (2,3)
      apply2q<1,8>(psi, M);   // pair (3,0)
    }
#pragma unroll
    for (int k = 0; k < 16; ++k) { Ur[k*17+t] = psi[k].x; Ui[k*17+t] = psi[k].y; }
  }
  __syncthreads();
  {
    int i = t >> 4, j = t & 15;
    float a0=0.f,a1=0.f,a2=0.f,a3=0.f;
#pragma unroll
    for (int k = 0; k < 16; ++k) {
      float pr = Ur[k*17+i]*Ur[k*17+j] + Ui[k*17+i]*Ui[k*17+j];
      a0 += ((k>>3)&1) ? -pr : pr;
      a1 += ((k>>2)&1) ? -pr : pr;
      a2 += ((k>>1)&1) ? -pr : pr;
      a3 += ( k     &1) ? -pr : pr;
    }
    A[0*256 + t] = a0; A[1*256 + t] = a1; A[2*256 + t] = a2; A[3*256 + t] = a3;
  }
}

// ------- Ktrans: FC transposes + conv2 f16 pack + conv1 f16 pack -------
__global__ __launch_bounds__(256) void k_trans(const float* __restrict__ w1a, const float* __restrict__ w1b,
                                               const float* __restrict__ w2a, const float* __restrict__ w2b,
                                               const float* __restrict__ c2w,
                                               const float* __restrict__ c1w, const float* __restrict__ c1b,
                                               float* __restrict__ wt) {
  int id = blockIdx.x*256 + threadIdx.x;
  if (id < 16384) { int j = id >> 6, o = id & 63;  wt[id] = w1a[o*256 + j]; return; }
  int id1 = id - 16384;
  if (id1 < 8192)  { int j = id1 >> 7, o = id1 & 127; wt[16384 + id1] = w1b[o*64 + j]; return; }
  int id2 = id1 - 8192;
  if (id2 < 8192)  { int j = id2 >> 6, o = id2 & 63;  wt[24576 + id2] = w2a[o*128 + j]; return; }
  int id3 = id2 - 8192;
  if (id3 < 640)   { int j = id3 / 10, o = id3 % 10;  wt[32768 + id3] = w2b[o*64 + j]; return; }
  int id4 = id3 - 640;
  if (id4 < 4608) {
    int p = id4 / 144, rr = id4 - p*144;
    int oc = rr / 9, k = rr - oc*9;
    float lo = c2w[oc*576 + p*9 + k];
    float hi = c2w[oc*576 + (p+32)*9 + k];
    ((unsigned*)wt)[33408 + id4] = packh2(lo, hi);
    return;
  }
  int id5 = id4 - 4608;
  if (id5 < 1024) {
    int oc = id5 >> 4, s = id5 & 15;
    unsigned v;
    if (s < 13)      v = packh2(c1w[oc*27 + 2*s], c1w[oc*27 + 2*s + 1]);
    else if (s == 13) v = __builtin_bit_cast(unsigned, c1w[oc*27 + 26]);
    else if (s == 14) v = __builtin_bit_cast(unsigned, c1b[oc]);
    else             v = 0u;
    ((unsigned*)wt)[38016 + id5] = v;
  }
}

// ---- K1: conv1(3->64)+relu+pool, v3: f16 fdot2 (13 pairs + 1 fp32 leftover). ----
__global__ __launch_bounds__(256) void k_conv1(const float* __restrict__ x,
                                               const unsigned* __restrict__ w1p,
                                               unsigned* __restrict__ h1p) {
  __shared__ float xs[3*32*32];
  int bid = blockIdx.x, b = bid >> 1, oh = bid & 1, tid = threadIdx.x;
  const float4* xsrc = (const float4*)(x + (size_t)b*3072);
  float4* xd = (float4*)xs;
#pragma unroll
  for (int k = 0; k < 3; ++k) xd[tid + k*256] = xsrc[tid + k*256];
  __syncthreads();
  int y = tid >> 4, xo = tid & 15;
  int y2 = y*2, x2 = xo*2;
  float in[3][4][4];
#pragma unroll
  for (int c = 0; c < 3; ++c)
#pragma unroll
    for (int ky = 0; ky < 4; ++ky) {
      int iy = y2 + ky - 1;
      bool vy = ((unsigned)iy < 32u);
      int iyc = vy ? iy : 0;
#pragma unroll
      for (int kx = 0; kx < 4; ++kx) {
        int ix = x2 + kx - 1;
        bool v = vy && ((unsigned)ix < 32u);
        int ixc = ((unsigned)ix < 32u) ? ix : 0;
        float val = xs[c*1024 + iyc*32 + ixc];
        in[c][ky][kx] = v ? val : 0.f;
      }
    }
  half2_t pk[4][13];
  float l26[4];
#pragma unroll
  for (int pos = 0; pos < 4; ++pos) {
    int dy = pos >> 1, dx = pos & 1;
#pragma unroll
    for (int i = 0; i < 13; ++i) {
      int e0 = 2*i, e1 = 2*i + 1;
      float v0 = in[e0/9][(e0%9)/3 + dy][e0%3 + dx];
      float v1 = in[e1/9][(e1%9)/3 + dy][e1%3 + dx];
      pk[pos][i] = __builtin_bit_cast(half2_t, packh2(v0, v1));
    }
    l26[pos] = in[2][2+dy][2+dx];
  }
  unsigned* outp = h1p + (size_t)b*8192 + tid;
  int p0 = oh*16;
  for (int pi = 0; pi < 16; ++pi) {
    int p = p0 + pi;
    const unsigned* wa = w1p + p*16;        // wave-uniform -> s_load
    const unsigned* wb = w1p + (p+32)*16;
    float ba = __builtin_bit_cast(float, wa[14]);
    float bb = __builtin_bit_cast(float, wb[14]);
    float A0=ba, A1=ba, A2=ba, A3=ba;
    float C0=bb, C1=bb, C2=bb, C3=bb;
#pragma unroll
    for (int i = 0; i < 13; ++i) {
      half2_t wha = __builtin_bit_cast(half2_t, wa[i]);
      half2_t whb = __builtin_bit_cast(half2_t, wb[i]);
      A0 = __builtin_amdgcn_fdot2(pk[0][i], wha, A0, false);
      A1 = __builtin_amdgcn_fdot2(pk[1][i], wha, A1, false);
      A2 = __builtin_amdgcn_fdot2(pk[2][i], wha, A2, false);
      A3 = __builtin_amdgcn_fdot2(pk[3][i], wha, A3, false);
      C0 = __builtin_amdgcn_fdot2(pk[0][i], whb, C0, false);
      C1 = __builtin_amdgcn_fdot2(pk[1][i], whb, C1, false);
      C2 = __builtin_amdgcn_fdot2(pk[2][i], whb, C2, false);
      C3 = __builtin_amdgcn_fdot2(pk[3][i], whb, C3, false);
    }
    float w26a = __builtin_bit_cast(float, wa[13]);
    float w26b = __builtin_bit_cast(float, wb[13]);
    A0 = fmaf(w26a, l26[0], A0); A1 = fmaf(w26a, l26[1], A1);
    A2 = fmaf(w26a, l26[2], A2); A3 = fmaf(w26a, l26[3], A3);
    C0 = fmaf(w26b, l26[0], C0); C1 = fmaf(w26b, l26[1], C1);
    C2 = fmaf(w26b, l26[2], C2); C3 = fmaf(w26b, l26[3], C3);
    float ma = fmaxf(fmaxf(fmaxf(A0,A1), fmaxf(A2,A3)), 0.f);
    float mb = fmaxf(fmaxf(fmaxf(C0,C1), fmaxf(C2,C3)), 0.f);
    outp[p*256] = packh2(ma, mb);
  }
}

// ---- K2: conv2(64->16)+relu+pool, v9: v7 (measured 48.5us) + aligned staging. ----
// LDS [32 pair][10 rows][24 u32] = 30720 B -> 5 blocks/CU. Data at u32 index
// 4..19 (halos 3/20 zero, guards 0..2/21..23 zero) so staging writes are
// 16B-aligned uint4. Reads: bank = 24r + x + C, lanes 4r x 16x -> every bank
// exactly 2 lanes, conflict-free. Same accumulation order -> bit-identical h2.
__global__ __launch_bounds__(256) void k_conv2(const unsigned* __restrict__ h1p,
                                               const unsigned* __restrict__ w2p,
                                               const float* __restrict__ bias, float* __restrict__ h2) {
  __shared__ unsigned hsp[32*10*24];   // 7680 u32 = 30720 B
  int bid = blockIdx.x, b = bid >> 1, h = bid & 1, t = threadIdx.x;
  {
    uint4 z = make_uint4(0u,0u,0u,0u);
    uint4* hz = (uint4*)hsp;
    for (int i = t; i < 1920; i += 256) hz[i] = z;
  }
  __syncthreads();
  // stage 9 valid rows as aligned uint4: local row = row9 + (1-h), global row = 7h + row9
  const uint4* src = (const uint4*)(h1p + (size_t)b*8192);   // [32 pair][16 rows][4 uint4]
  uint4* dst4 = (uint4*)hsp;           // row = 6 uint4; data slots 1..4
#pragma unroll
  for (int k = 0; k < 5; ++k) {
    int idx = t + k*256;               // 0..1151
    if (idx < 1152) {
      int p = idx / 36, rem = idx - p*36;
      int row9 = rem >> 2, c4 = rem & 3;
      dst4[p*60 + (row9 + 1 - h)*6 + 1 + c4] = src[p*64 + (7*h + row9)*4 + c4];
    }
  }
  __syncthreads();
  int ocg = __builtin_amdgcn_readfirstlane((int)(t >> 7));   // wave-uniform
  int pos = t & 127;
  int yl = pos >> 4, x = pos & 15;     // conv row yl (0..7) within this half
  float acc[8];
#pragma unroll
  for (int o = 0; o < 8; ++o) acc[o] = bias[ocg*8 + o];
#pragma unroll 2
  for (int p = 0; p < 32; ++p) {
    unsigned in9[9];
#pragma unroll
    for (int dy = 0; dy < 3; ++dy)
#pragma unroll
      for (int kx = 0; kx < 3; ++kx)
        in9[dy*3+kx] = hsp[p*240 + (yl+dy)*24 + 3 + x + kx];
    const unsigned* wp = w2p + p*144 + ocg*72;   // wave-uniform -> s_load
#pragma unroll
    for (int o = 0; o < 8; ++o)
#pragma unroll
      for (int k9 = 0; k9 < 9; ++k9)
        acc[o] = __builtin_amdgcn_fdot2(__builtin_bit_cast(half2_t, in9[k9]),
                                        __builtin_bit_cast(half2_t, wp[o*9+k9]),
                                        acc[o], false);
  }
  // 2x2 maxpool: x^1 via lane^1, yl^1 via lane^16; relu + write
  bool writer = ((yl & 1) == 0) && ((x & 1) == 0);
  int py = h*4 + (yl >> 1), px = x >> 1;
  float* outb = h2 + (size_t)b*1024;
#pragma unroll
  for (int o = 0; o < 8; ++o) {
    float m = fmaxf(acc[o], __shfl_xor(acc[o], 1, 64));
    m = fmaxf(m, __shfl_xor(m, 16, 64));
    if (writer) outb[(ocg*8+o)*64 + py*8 + px] = fmaxf(m, 0.f);
  }
}

// ---- Ktail: conv3(16->4)+leaky+sigmoid*pi -> quantum forms -> full FC chain ----
// Block handles 4 images == 4 q-rows == 4 fc rows. q stays in LDS.
__global__ __launch_bounds__(256) void k_tail(const float* __restrict__ h2, const float* __restrict__ w,
                                              const float* __restrict__ bias, const float* __restrict__ Ag,
                                              const float* __restrict__ wt,
                                              const float* __restrict__ b1a, const float* __restrict__ b1b,
                                              const float* __restrict__ b2a, const float* __restrict__ b2b,
                                              float* __restrict__ out) {
  __shared__ float S[8448];
  float* h3s = S;                      // [4][16][10][10] = 6400 (overlaid by fc S later)
  float* qs  = S + 6400;               // [4][256] = 1024
  float* As  = S + 7424;               // [4][256] = 1024
  int b4 = blockIdx.x*4, t = threadIdx.x;
#pragma unroll
  for (int k = 0; k < 4; ++k) As[t + k*256] = Ag[t + k*256];
  for (int i = t; i < 6400; i += 256) h3s[i] = 0.f;
  __syncthreads();
  int img = t >> 6, lane = t & 63;
  {
    const float4* src = (const float4*)(h2 + (size_t)(b4+img)*1024);
#pragma unroll
    for (int k = 0; k < 4; ++k) {
      float4 v = src[lane + k*64];
      int e = 4*(lane + k*64);
      int ic = e >> 6, iy = (e >> 3) & 7, ix = e & 7;
      float* d = &h3s[img*1600 + ic*100 + (iy+1)*10 + ix + 1];
      d[0]=v.x; d[1]=v.y; d[2]=v.z; d[3]=v.w;
    }
  }
  __syncthreads();
  {
    int y = lane >> 3, xo = lane & 7;
    float acc[4];
#pragma unroll
    for (int o = 0; o < 4; ++o) acc[o] = bias[o];
    for (int ic = 0; ic < 16; ++ic) {
      float in[3][3];
#pragma unroll
      for (int ky = 0; ky < 3; ++ky)
#pragma unroll
        for (int kx = 0; kx < 3; ++kx)
          in[ky][kx] = h3s[img*1600 + ic*100 + (y+ky)*10 + (xo+kx)];
#pragma unroll
      for (int o = 0; o < 4; ++o) {
        const float* wp = w + (o*16 + ic)*9;
#pragma unroll
        for (int ky = 0; ky < 3; ++ky)
#pragma unroll
          for (int kx = 0; kx < 3; ++kx)
            acc[o] = fmaf(wp[ky*3+kx], in[ky][kx], acc[o]);
      }
    }
    float v0[2], v1[2], v2[2], v3[2];
#pragma unroll
    for (int o = 0; o < 4; ++o) {
      float v = acc[o];
      float l = v > 0.f ? v : 0.01f*v;
      float sg = 1.f/(1.f + expf(-l));
      float sv, cv;
      __sincosf(sg * (0.5f*PI_F), &sv, &cv);
      float* dst = (o==0)?v0:(o==1)?v1:(o==2)?v2:v3;
      dst[0] = cv; dst[1] = sv;
    }
    float pv[16];
#pragma unroll
    for (int i = 0; i < 16; ++i)
      pv[i] = v0[(i>>3)&1] * v1[(i>>2)&1] * v2[(i>>1)&1] * v3[i&1];
#pragma unroll
    for (int w4 = 0; w4 < 4; ++w4) {
      const float4* Aw = (const float4*)(As + w4*256);
      float a = 0.f;
#pragma unroll
      for (int i = 0; i < 16; ++i) {
        float d = 0.f;
#pragma unroll
        for (int j4 = 0; j4 < 4; ++j4) {
          float4 av = Aw[i*4 + j4];
          d = fmaf(av.x, pv[j4*4+0], d);
          d = fmaf(av.y, pv[j4*4+1], d);
          d = fmaf(av.z, pv[j4*4+2], d);
          d = fmaf(av.w, pv[j4*4+3], d);
        }
        a = fmaf(pv[i], d, a);
      }
      qs[img*256 + lane*4 + w4] = a;
    }
  }
  __syncthreads();
  // ---- FC phase: wave wv owns row b4+wv; S-work region overlays h3s ----
  int wv = img;
  float* Sw = S + wv*512;
  ((float4*)Sw)[lane] = ((const float4*)(qs + wv*256))[lane];
  __syncthreads();
  const float* WT1a = wt;
  const float* WT1b = wt + 16384;
  const float* WT2a = wt + 24576;
  const float* WT2b = wt + 32768;
  float acc = b1a[lane];
  for (int j = 0; j < 256; ++j) acc = fmaf(WT1a[j*64+lane], Sw[j], acc);
  float hR = fmaxf(acc, 0.f);
  __syncthreads();
  Sw[256+lane] = hR;
  __syncthreads();
  float a0 = b1b[lane], a1 = b1b[64+lane];
  for (int j = 0; j < 64; ++j) {
    float sj = Sw[256+j];
    a0 = fmaf(WT1b[j*128+lane],    sj, a0);
    a1 = fmaf(WT1b[j*128+64+lane], sj, a1);
  }
  __syncthreads();
  Sw[320+lane] = a0; Sw[384+lane] = a1;
  __syncthreads();
  float c2a = b2a[lane];
  for (int j = 0; j < 128; ++j) c2a = fmaf(WT2a[j*64+lane], Sw[320+j], c2a);
  float h2v = fmaxf(c2a, 0.f);
  __syncthreads();
  Sw[448+lane] = h2v;
  __syncthreads();
  if (lane < 10) {
    float o = b2b[lane];
    for (int j = 0; j < 64; ++j) o = fmaf(WT2b[j*10+lane], Sw[448+j], o);
    out[(size_t)(b4+wv)*10 + lane] = o;
  }
}

extern "C" void kernel_launch(void* const* d_in, const int* in_sizes, int n_in,
                              void* d_out, int out_size, void* d_ws, size_t ws_size,
                              hipStream_t stream) {
  const float* x       = (const float*)d_in[0];
  const float* conv1_w = (const float*)d_in[1];
  const float* conv1_b = (const float*)d_in[2];
  const float* conv2_w = (const float*)d_in[3];
  const float* conv2_b = (const float*)d_in[4];
  const float* conv3_w = (const float*)d_in[5];
  const float* conv3_b = (const float*)d_in[6];
  const float* qw_u3   = (const float*)d_in[7];
  const float* qw_ang  = (const float*)d_in[8];
  const float* fc1a_w  = (const float*)d_in[9];
  const float* fc1a_b  = (const float*)d_in[10];
  const float* fc1b_w  = (const float*)d_in[11];
  const float* fc1b_b  = (const float*)d_in[12];
  const float* fc2a_w  = (const float*)d_in[13];
  const float* fc2a_b  = (const float*)d_in[14];
  const float* fc2b_w  = (const float*)d_in[15];
  const float* fc2b_b  = (const float*)d_in[16];
  float* out = (float*)d_out;

  float* ws  = (float*)d_ws;
  float* A   = ws;                      // 1024 floats
  float* WT  = ws + 1024;               // fc transposes (33408 f32) + conv2 pk (4608 u32) + conv1 pk (1024 u32)
  const unsigned* W2P = (const unsigned*)WT + 33408;
  const unsigned* W1P = (const unsigned*)WT + 38016;
  unsigned* h1p = (unsigned*)(ws + 305792);  // 8388608 u32 (1024 x 32pair x 16 x 16)
  float* h2  = ws + 17083008;           // 1048576 floats  (1024x16x8x8)

  k_qmat  <<<1,    256, 0, stream>>>(qw_u3, qw_ang, A);
  k_trans <<<167,  256, 0, stream>>>(fc1a_w, fc1b_w, fc2a_w, fc2b_w, conv2_w, conv1_w, conv1_b, WT);
  k_conv1 <<<2048, 256, 0, stream>>>(x, W1P, h1p);
  k_conv2 <<<2048, 256, 0, stream>>>(h1p, W2P, conv2_b, h2);
  k_tail  <<<256,  256, 0, stream>>>(h2, conv3_w, conv3_b, A, WT,
                                     fc1a_b, fc1b_b, fc2a_b, fc2b_b, out);
}

// Round 14
// 96.209 us; speedup vs baseline: 1.4362x; 1.2990x over previous
//
#include <hip/hip_runtime.h>
#include <math.h>

#define PI_F 3.14159265358979323846f

typedef _Float16 half2_t __attribute__((ext_vector_type(2)));
typedef _Float16 f16x8 __attribute__((ext_vector_type(8)));
typedef float f32x4v __attribute__((ext_vector_type(4)));

__device__ __forceinline__ unsigned packh2(float lo, float hi) {
  unsigned short l = __builtin_bit_cast(unsigned short, (_Float16)lo);
  unsigned short h = __builtin_bit_cast(unsigned short, (_Float16)hi);
  return (unsigned)l | ((unsigned)h << 16);
}

struct c2 { float x, y; };
__device__ __forceinline__ c2 cmul(c2 a, c2 b){ return c2{a.x*b.x - a.y*b.y, a.x*b.y + a.y*b.x}; }
__device__ __forceinline__ c2 cadd(c2 a, c2 b){ return c2{a.x+b.x, a.y+b.y}; }

__device__ __forceinline__ void rot2(c2 &a, c2 &b, c2 g00, c2 g01, c2 g10, c2 g11) {
  c2 na = cadd(cmul(g00,a), cmul(g01,b));
  c2 nb = cadd(cmul(g10,a), cmul(g11,b));
  a = na; b = nb;
}

__device__ __forceinline__ void mk_u3(float th, float ph, float la,
                                      c2 &g00, c2 &g01, c2 &g10, c2 &g11) {
  float ch = cosf(0.5f*th), sh = sinf(0.5f*th);
  float cl = cosf(la), sl = sinf(la);
  float cp = cosf(ph), sp = sinf(ph);
  float cpl = cp*cl - sp*sl, spl = sp*cl + cp*sl;
  g00 = c2{ch, 0.f};
  g01 = c2{-cl*sh, -sl*sh};
  g10 = c2{cp*sh, sp*sh};
  g11 = c2{cpl*ch, spl*ch};
}

template<int MA, int MB>
__device__ __forceinline__ void apply2q(c2 psi[16], const c2 M[16]) {
#pragma unroll
  for (int r = 0; r < 16; ++r) {
    if (r & (MA | MB)) continue;
    c2 a = psi[r], b = psi[r|MB], c = psi[r|MA], d = psi[r|MA|MB];
    psi[r]        = cadd(cadd(cmul(M[0],a),  cmul(M[1],b)),  cadd(cmul(M[2],c),  cmul(M[3],d)));
    psi[r|MB]     = cadd(cadd(cmul(M[4],a),  cmul(M[5],b)),  cadd(cmul(M[6],c),  cmul(M[7],d)));
    psi[r|MA]     = cadd(cadd(cmul(M[8],a),  cmul(M[9],b)),  cadd(cmul(M[10],c), cmul(M[11],d)));
    psi[r|MA|MB]  = cadd(cadd(cmul(M[12],a), cmul(M[13],b)), cadd(cmul(M[14],c), cmul(M[15],d)));
  }
}

// ---------------- K0: build A_w = Re(U^dag Z_w U), 4 x 16 x 16 ----------------
__global__ __launch_bounds__(256) void k_qmat(const float* __restrict__ qw_u3,
                                              const float* __restrict__ qw_ang,
                                              float* __restrict__ A) {
  __shared__ c2 SU[2][16];
  __shared__ float Ur[16*17], Ui[16*17];
  int t = threadIdx.x;
  if (t < 8) {
    int L = t >> 2, col = t & 3;
    c2 s[4];
#pragma unroll
    for (int i = 0; i < 4; ++i) s[i] = c2{(i==col)?1.f:0.f, 0.f};
    const float* u = qw_u3 + 12*L;
    const float* g = qw_ang + 3*L;
    c2 g00,g01,g10,g11;
    mk_u3(u[0],u[1],u[2], g00,g01,g10,g11);             // u3s[0] on a (mask 2)
    rot2(s[0],s[2], g00,g01,g10,g11); rot2(s[1],s[3], g00,g01,g10,g11);
    mk_u3(u[3],u[4],u[5], g00,g01,g10,g11);             // u3s[1] on b (mask 1)
    rot2(s[0],s[1], g00,g01,g10,g11); rot2(s[2],s[3], g00,g01,g10,g11);
    { c2 tmp = s[2]; s[2] = s[3]; s[3] = tmp; }          // CNOT a->b
    { float c = cosf(0.5f*g[0]), sn = sinf(0.5f*g[0]);
      c2 r00{c,0.f}, r01{-sn,0.f}, r10{sn,0.f}, r11{c,0.f};
      rot2(s[0],s[2], r00,r01,r10,r11); rot2(s[1],s[3], r00,r01,r10,r11); } // RY on a
    { float c = cosf(0.5f*g[1]), sn = sinf(0.5f*g[1]);
      c2 e0{c,-sn}, e1{c,sn};
      s[0]=cmul(s[0],e0); s[1]=cmul(s[1],e1); s[2]=cmul(s[2],e0); s[3]=cmul(s[3],e1); } // RZ on b
    { c2 tmp = s[1]; s[1] = s[3]; s[3] = tmp; }          // CNOT b->a
    { float c = cosf(0.5f*g[2]), sn = sinf(0.5f*g[2]);
      c2 r00{c,0.f}, r01{-sn,0.f}, r10{sn,0.f}, r11{c,0.f};
      rot2(s[0],s[2], r00,r01,r10,r11); rot2(s[1],s[3], r00,r01,r10,r11); } // RY on a
    { c2 tmp = s[2]; s[2] = s[3]; s[3] = tmp; }          // CNOT a->b
    mk_u3(u[6],u[7],u[8], g00,g01,g10,g11);             // u3s[2] on a
    rot2(s[0],s[2], g00,g01,g10,g11); rot2(s[1],s[3], g00,g01,g10,g11);
    mk_u3(u[9],u[10],u[11], g00,g01,g10,g11);           // u3s[3] on b
    rot2(s[0],s[1], g00,g01,g10,g11); rot2(s[2],s[3], g00,g01,g10,g11);
#pragma unroll
    for (int k = 0; k < 4; ++k) SU[L][k*4 + col] = s[k];
  }
  __syncthreads();
  if (t < 16) {
    c2 psi[16];
#pragma unroll
    for (int i = 0; i < 16; ++i) psi[i] = c2{(i==t)?1.f:0.f, 0.f};
#pragma unroll
    for (int l = 0; l < 2; ++l) {
      c2 M[16];
#pragma unroll
      for (int k = 0; k < 16; ++k) M[k] = SU[l][k];
      apply2q<8,4>(psi, M);   // pair (0,1)
      apply2q<4,2>(psi, M);   // pair (1,2)
      apply2q<2,1>(psi, M);   // pair (2,3)
      apply2q<1,8>(psi, M);   // pair (3,0)
    }
#pragma unroll
    for (int k = 0; k < 16; ++k) { Ur[k*17+t] = psi[k].x; Ui[k*17+t] = psi[k].y; }
  }
  __syncthreads();
  {
    int i = t >> 4, j = t & 15;
    float a0=0.f,a1=0.f,a2=0.f,a3=0.f;
#pragma unroll
    for (int k = 0; k < 16; ++k) {
      float pr = Ur[k*17+i]*Ur[k*17+j] + Ui[k*17+i]*Ui[k*17+j];
      a0 += ((k>>3)&1) ? -pr : pr;
      a1 += ((k>>2)&1) ? -pr : pr;
      a2 += ((k>>1)&1) ? -pr : pr;
      a3 += ( k     &1) ? -pr : pr;
    }
    A[0*256 + t] = a0; A[1*256 + t] = a1; A[2*256 + t] = a2; A[3*256 + t] = a3;
  }
}

// ------- Ktrans: FC transposes + conv2 MFMA B-frag pack + conv1 f16 pack -------
// Bg layout: [18 slices][64 lanes][4 u32]; slice s: tap=s>>1, h=s&1.
// Lane l: oc=l&15, j=l>>4. Reg r: lo = w2[oc][16h+4j+r][tap], hi = +32 ic.
__global__ __launch_bounds__(256) void k_trans(const float* __restrict__ w1a, const float* __restrict__ w1b,
                                               const float* __restrict__ w2a, const float* __restrict__ w2b,
                                               const float* __restrict__ c2w,
                                               const float* __restrict__ c1w, const float* __restrict__ c1b,
                                               float* __restrict__ wt) {
  int id = blockIdx.x*256 + threadIdx.x;
  if (id < 16384) { int j = id >> 6, o = id & 63;  wt[id] = w1a[o*256 + j]; return; }
  int id1 = id - 16384;
  if (id1 < 8192)  { int j = id1 >> 7, o = id1 & 127; wt[16384 + id1] = w1b[o*64 + j]; return; }
  int id2 = id1 - 8192;
  if (id2 < 8192)  { int j = id2 >> 6, o = id2 & 63;  wt[24576 + id2] = w2a[o*128 + j]; return; }
  int id3 = id2 - 8192;
  if (id3 < 640)   { int j = id3 / 10, o = id3 % 10;  wt[32768 + id3] = w2b[o*64 + j]; return; }
  int id4 = id3 - 640;
  if (id4 < 4608) {
    int s = id4 >> 8, rem = id4 & 255, l = rem >> 2, r = rem & 3;
    int tap = s >> 1, h = s & 1;
    int oc = l & 15, j = l >> 4;
    int icl = 16*h + 4*j + r;
    float lo = c2w[oc*576 + icl*9 + tap];
    float hi = c2w[oc*576 + (icl+32)*9 + tap];
    ((unsigned*)wt)[33408 + id4] = packh2(lo, hi);
    return;
  }
  int id5 = id4 - 4608;
  if (id5 < 1024) {
    int oc = id5 >> 4, s = id5 & 15;
    unsigned v;
    if (s < 13)      v = packh2(c1w[oc*27 + 2*s], c1w[oc*27 + 2*s + 1]);
    else if (s == 13) v = __builtin_bit_cast(unsigned, c1w[oc*27 + 26]);
    else if (s == 14) v = __builtin_bit_cast(unsigned, c1b[oc]);
    else             v = 0u;
    ((unsigned*)wt)[38016 + id5] = v;
  }
}

// ---- K1: conv1(3->64)+relu+pool, v3: f16 fdot2 (13 pairs + 1 fp32 leftover). ----
__global__ __launch_bounds__(256) void k_conv1(const float* __restrict__ x,
                                               const unsigned* __restrict__ w1p,
                                               unsigned* __restrict__ h1p) {
  __shared__ float xs[3*32*32];
  int bid = blockIdx.x, b = bid >> 1, oh = bid & 1, tid = threadIdx.x;
  const float4* xsrc = (const float4*)(x + (size_t)b*3072);
  float4* xd = (float4*)xs;
#pragma unroll
  for (int k = 0; k < 3; ++k) xd[tid + k*256] = xsrc[tid + k*256];
  __syncthreads();
  int y = tid >> 4, xo = tid & 15;
  int y2 = y*2, x2 = xo*2;
  float in[3][4][4];
#pragma unroll
  for (int c = 0; c < 3; ++c)
#pragma unroll
    for (int ky = 0; ky < 4; ++ky) {
      int iy = y2 + ky - 1;
      bool vy = ((unsigned)iy < 32u);
      int iyc = vy ? iy : 0;
#pragma unroll
      for (int kx = 0; kx < 4; ++kx) {
        int ix = x2 + kx - 1;
        bool v = vy && ((unsigned)ix < 32u);
        int ixc = ((unsigned)ix < 32u) ? ix : 0;
        float val = xs[c*1024 + iyc*32 + ixc];
        in[c][ky][kx] = v ? val : 0.f;
      }
    }
  half2_t pk[4][13];
  float l26[4];
#pragma unroll
  for (int pos = 0; pos < 4; ++pos) {
    int dy = pos >> 1, dx = pos & 1;
#pragma unroll
    for (int i = 0; i < 13; ++i) {
      int e0 = 2*i, e1 = 2*i + 1;
      float v0 = in[e0/9][(e0%9)/3 + dy][e0%3 + dx];
      float v1 = in[e1/9][(e1%9)/3 + dy][e1%3 + dx];
      pk[pos][i] = __builtin_bit_cast(half2_t, packh2(v0, v1));
    }
    l26[pos] = in[2][2+dy][2+dx];
  }
  unsigned* outp = h1p + (size_t)b*8192 + tid;
  int p0 = oh*16;
  for (int pi = 0; pi < 16; ++pi) {
    int p = p0 + pi;
    const unsigned* wa = w1p + p*16;        // wave-uniform -> s_load
    const unsigned* wb = w1p + (p+32)*16;
    float ba = __builtin_bit_cast(float, wa[14]);
    float bb = __builtin_bit_cast(float, wb[14]);
    float A0=ba, A1=ba, A2=ba, A3=ba;
    float C0=bb, C1=bb, C2=bb, C3=bb;
#pragma unroll
    for (int i = 0; i < 13; ++i) {
      half2_t wha = __builtin_bit_cast(half2_t, wa[i]);
      half2_t whb = __builtin_bit_cast(half2_t, wb[i]);
      A0 = __builtin_amdgcn_fdot2(pk[0][i], wha, A0, false);
      A1 = __builtin_amdgcn_fdot2(pk[1][i], wha, A1, false);
      A2 = __builtin_amdgcn_fdot2(pk[2][i], wha, A2, false);
      A3 = __builtin_amdgcn_fdot2(pk[3][i], wha, A3, false);
      C0 = __builtin_amdgcn_fdot2(pk[0][i], whb, C0, false);
      C1 = __builtin_amdgcn_fdot2(pk[1][i], whb, C1, false);
      C2 = __builtin_amdgcn_fdot2(pk[2][i], whb, C2, false);
      C3 = __builtin_amdgcn_fdot2(pk[3][i], whb, C3, false);
    }
    float w26a = __builtin_bit_cast(float, wa[13]);
    float w26b = __builtin_bit_cast(float, wb[13]);
    A0 = fmaf(w26a, l26[0], A0); A1 = fmaf(w26a, l26[1], A1);
    A2 = fmaf(w26a, l26[2], A2); A3 = fmaf(w26a, l26[3], A3);
    C0 = fmaf(w26b, l26[0], C0); C1 = fmaf(w26b, l26[1], C1);
    C2 = fmaf(w26b, l26[2], C2); C3 = fmaf(w26b, l26[3], C3);
    float ma = fmaxf(fmaxf(fmaxf(A0,A1), fmaxf(A2,A3)), 0.f);
    float mb = fmaxf(fmaxf(fmaxf(C0,C1), fmaxf(C2,C3)), 0.f);
    outp[p*256] = packh2(ma, mb);
  }
}

// ---- K2: conv2(64->16)+relu+pool, v10: implicit-GEMM via MFMA 16x16x32 f16. ----
// One image/block. M=256 pos, N=16 oc, K=576 (tap-major, free ic-perm).
// LDS im2col [18 ry][18 rx][36 slot] u32 (pixel stride 36 -> conflict-free b128
// reads AND writes). Wave w: 4 M-tiles (y = 4w+t, x = lane&15). B-frags
// preloaded (18 uint4/lane). Pooling fully in-lane (x-pairs = regs, y-pairs =
// tiles). A-frag: lane(pos x=l&15, j=l>>4) reads pairs [16h+4j..+3] of pixel
// (y+dy, x+dx) -> f16 seq ic = {16h+4j+q, +32} matches Bg pack.
__global__ __launch_bounds__(256) void k_conv2(const unsigned* __restrict__ h1p,
                                               const uint4* __restrict__ Bg,
                                               const float* __restrict__ bias, float* __restrict__ h2) {
  __shared__ unsigned hsp[18*18*36];   // 11664 u32 = 46656 B
  int b = blockIdx.x, t = threadIdx.x;
  {
    uint4 z = make_uint4(0u,0u,0u,0u);
    uint4* hz = (uint4*)hsp;
    for (int i = t; i < 2916; i += 256) hz[i] = z;
  }
  int l = t & 63, w = t >> 6;
  int xcol = l & 15, j = l >> 4;
  // preload B fragments (global, L2-resident, coalesced)
  uint4 Bf[18];
#pragma unroll
  for (int s = 0; s < 18; ++s) Bf[s] = Bg[s*64 + l];
  __syncthreads();
  // stage: thread t owns pixel t (ry=t>>4, rx=t&15); k-th iter: pairs 4k..4k+3
  {
    const unsigned* src = h1p + (size_t)b*8192;
    int ry = t >> 4, rx = t & 15;
    unsigned* dp = &hsp[((ry+1)*18 + rx+1)*36];
#pragma unroll
    for (int k = 0; k < 8; ++k) {
      unsigned q0 = src[(4*k+0)*256 + t];
      unsigned q1 = src[(4*k+1)*256 + t];
      unsigned q2 = src[(4*k+2)*256 + t];
      unsigned q3 = src[(4*k+3)*256 + t];
      *(uint4*)(dp + 4*k) = make_uint4(q0, q1, q2, q3);
    }
  }
  __syncthreads();
  float bz = bias[xcol];
  f32x4v acc[4];
#pragma unroll
  for (int tt = 0; tt < 4; ++tt) acc[tt] = f32x4v{bz, bz, bz, bz};
#pragma unroll
  for (int s = 0; s < 18; ++s) {
    const int tap = s >> 1, h = s & 1;
    const int dy = tap / 3, dx = tap % 3;
    f16x8 Bv = __builtin_bit_cast(f16x8, Bf[s]);
#pragma unroll
    for (int tt = 0; tt < 4; ++tt) {
      int y = 4*w + tt;
      f16x8 Av = __builtin_bit_cast(f16x8,
          *(const uint4*)&hsp[((y+dy)*18 + xcol+dx)*36 + 16*h + 4*j]);
      acc[tt] = __builtin_amdgcn_mfma_f32_16x16x32_f16(Av, Bv, acc[tt], 0, 0, 0);
    }
  }
  // pool 2x2 in-lane: y-pairs = tile pairs, x-pairs = reg pairs; relu + write
  float* outb = h2 + (size_t)b*1024 + xcol*64;
#pragma unroll
  for (int tp = 0; tp < 2; ++tp)
#pragma unroll
    for (int vp = 0; vp < 2; ++vp) {
      float m = fmaxf(fmaxf(acc[2*tp][2*vp], acc[2*tp][2*vp+1]),
                      fmaxf(acc[2*tp+1][2*vp], acc[2*tp+1][2*vp+1]));
      int py = 2*w + tp, px = 2*j + vp;
      outb[py*8 + px] = fmaxf(m, 0.f);
    }
}

// ---- Ktail: conv3(16->4)+leaky+sigmoid*pi -> quantum forms -> full FC chain ----
__global__ __launch_bounds__(256) void k_tail(const float* __restrict__ h2, const float* __restrict__ w,
                                              const float* __restrict__ bias, const float* __restrict__ Ag,
                                              const float* __restrict__ wt,
                                              const float* __restrict__ b1a, const float* __restrict__ b1b,
                                              const float* __restrict__ b2a, const float* __restrict__ b2b,
                                              float* __restrict__ out) {
  __shared__ float S[8448];
  float* h3s = S;                      // [4][16][10][10] = 6400 (overlaid by fc S later)
  float* qs  = S + 6400;               // [4][256] = 1024
  float* As  = S + 7424;               // [4][256] = 1024
  int b4 = blockIdx.x*4, t = threadIdx.x;
#pragma unroll
  for (int k = 0; k < 4; ++k) As[t + k*256] = Ag[t + k*256];
  for (int i = t; i < 6400; i += 256) h3s[i] = 0.f;
  __syncthreads();
  int img = t >> 6, lane = t & 63;
  {
    const float4* src = (const float4*)(h2 + (size_t)(b4+img)*1024);
#pragma unroll
    for (int k = 0; k < 4; ++k) {
      float4 v = src[lane + k*64];
      int e = 4*(lane + k*64);
      int ic = e >> 6, iy = (e >> 3) & 7, ix = e & 7;
      float* d = &h3s[img*1600 + ic*100 + (iy+1)*10 + ix + 1];
      d[0]=v.x; d[1]=v.y; d[2]=v.z; d[3]=v.w;
    }
  }
  __syncthreads();
  {
    int y = lane >> 3, xo = lane & 7;
    float acc[4];
#pragma unroll
    for (int o = 0; o < 4; ++o) acc[o] = bias[o];
    for (int ic = 0; ic < 16; ++ic) {
      float in[3][3];
#pragma unroll
      for (int ky = 0; ky < 3; ++ky)
#pragma unroll
        for (int kx = 0; kx < 3; ++kx)
          in[ky][kx] = h3s[img*1600 + ic*100 + (y+ky)*10 + (xo+kx)];
#pragma unroll
      for (int o = 0; o < 4; ++o) {
        const float* wp = w + (o*16 + ic)*9;
#pragma unroll
        for (int ky = 0; ky < 3; ++ky)
#pragma unroll
          for (int kx = 0; kx < 3; ++kx)
            acc[o] = fmaf(wp[ky*3+kx], in[ky][kx], acc[o]);
      }
    }
    float v0[2], v1[2], v2[2], v3[2];
#pragma unroll
    for (int o = 0; o < 4; ++o) {
      float v = acc[o];
      float l = v > 0.f ? v : 0.01f*v;
      float sg = 1.f/(1.f + expf(-l));
      float sv, cv;
      __sincosf(sg * (0.5f*PI_F), &sv, &cv);
      float* dst = (o==0)?v0:(o==1)?v1:(o==2)?v2:v3;
      dst[0] = cv; dst[1] = sv;
    }
    float pv[16];
#pragma unroll
    for (int i = 0; i < 16; ++i)
      pv[i] = v0[(i>>3)&1] * v1[(i>>2)&1] * v2[(i>>1)&1] * v3[i&1];
#pragma unroll
    for (int w4 = 0; w4 < 4; ++w4) {
      const float4* Aw = (const float4*)(As + w4*256);
      float a = 0.f;
#pragma unroll
      for (int i = 0; i < 16; ++i) {
        float d = 0.f;
#pragma unroll
        for (int j4 = 0; j4 < 4; ++j4) {
          float4 av = Aw[i*4 + j4];
          d = fmaf(av.x, pv[j4*4+0], d);
          d = fmaf(av.y, pv[j4*4+1], d);
          d = fmaf(av.z, pv[j4*4+2], d);
          d = fmaf(av.w, pv[j4*4+3], d);
        }
        a = fmaf(pv[i], d, a);
      }
      qs[img*256 + lane*4 + w4] = a;
    }
  }
  __syncthreads();
  // ---- FC phase: wave wv owns row b4+wv; S-work region overlays h3s ----
  int wv = img;
  float* Sw = S + wv*512;
  ((float4*)Sw)[lane] = ((const float4*)(qs + wv*256))[lane];
  __syncthreads();
  const float* WT1a = wt;
  const float* WT1b = wt + 16384;
  const float* WT2a = wt + 24576;
  const float* WT2b = wt + 32768;
  float acc = b1a[lane];
  for (int j = 0; j < 256; ++j) acc = fmaf(WT1a[j*64+lane], Sw[j], acc);
  float hR = fmaxf(acc, 0.f);
  __syncthreads();
  Sw[256+lane] = hR;
  __syncthreads();
  float a0 = b1b[lane], a1 = b1b[64+lane];
  for (int j = 0; j < 64; ++j) {
    float sj = Sw[256+j];
    a0 = fmaf(WT1b[j*128+lane],    sj, a0);
    a1 = fmaf(WT1b[j*128+64+lane], sj, a1);
  }
  __syncthreads();
  Sw[320+lane] = a0; Sw[384+lane] = a1;
  __syncthreads();
  float c2a = b2a[lane];
  for (int j = 0; j < 128; ++j) c2a = fmaf(WT2a[j*64+lane], Sw[320+j], c2a);
  float h2v = fmaxf(c2a, 0.f);
  __syncthreads();
  Sw[448+lane] = h2v;
  __syncthreads();
  if (lane < 10) {
    float o = b2b[lane];
    for (int j = 0; j < 64; ++j) o = fmaf(WT2b[j*10+lane], Sw[448+j], o);
    out[(size_t)(b4+wv)*10 + lane] = o;
  }
}

extern "C" void kernel_launch(void* const* d_in, const int* in_sizes, int n_in,
                              void* d_out, int out_size, void* d_ws, size_t ws_size,
                              hipStream_t stream) {
  const float* x       = (const float*)d_in[0];
  const float* conv1_w = (const float*)d_in[1];
  const float* conv1_b = (const float*)d_in[2];
  const float* conv2_w = (const float*)d_in[3];
  const float* conv2_b = (const float*)d_in[4];
  const float* conv3_w = (const float*)d_in[5];
  const float* conv3_b = (const float*)d_in[6];
  const float* qw_u3   = (const float*)d_in[7];
  const float* qw_ang  = (const float*)d_in[8];
  const float* fc1a_w  = (const float*)d_in[9];
  const float* fc1a_b  = (const float*)d_in[10];
  const float* fc1b_w  = (const float*)d_in[11];
  const float* fc1b_b  = (const float*)d_in[12];
  const float* fc2a_w  = (const float*)d_in[13];
  const float* fc2a_b  = (const float*)d_in[14];
  const float* fc2b_w  = (const float*)d_in[15];
  const float* fc2b_b  = (const float*)d_in[16];
  float* out = (float*)d_out;

  float* ws  = (float*)d_ws;
  float* A   = ws;                      // 1024 floats
  float* WT  = ws + 1024;               // fc transposes (33408 f32) + conv2 B-frags (4608 u32) + conv1 pk (1024 u32)
  const uint4* BG = (const uint4*)((const unsigned*)WT + 33408);
  const unsigned* W1P = (const unsigned*)WT + 38016;
  unsigned* h1p = (unsigned*)(ws + 305792);  // 8388608 u32 (1024 x 32pair x 16 x 16)
  float* h2  = ws + 17083008;           // 1048576 floats  (1024x16x8x8)

  k_qmat  <<<1,    256, 0, stream>>>(qw_u3, qw_ang, A);
  k_trans <<<167,  256, 0, stream>>>(fc1a_w, fc1b_w, fc2a_w, fc2b_w, conv2_w, conv1_w, conv1_b, WT);
  k_conv1 <<<2048, 256, 0, stream>>>(x, W1P, h1p);
  k_conv2 <<<1024, 256, 0, stream>>>(h1p, BG, conv2_b, h2);
  k_tail  <<<256,  256, 0, stream>>>(h2, conv3_w, conv3_b, A, WT,
                                     fc1a_b, fc1b_b, fc2a_b, fc2b_b, out);
}

// Round 15
// 81.784 us; speedup vs baseline: 1.6895x; 1.1764x over previous
//
#include <hip/hip_runtime.h>
#include <math.h>

#define PI_F 3.14159265358979323846f

typedef _Float16 half2_t __attribute__((ext_vector_type(2)));
typedef _Float16 f16x8 __attribute__((ext_vector_type(8)));
typedef float f32x4v __attribute__((ext_vector_type(4)));

__device__ __forceinline__ unsigned packh2(float lo, float hi) {
  unsigned short l = __builtin_bit_cast(unsigned short, (_Float16)lo);
  unsigned short h = __builtin_bit_cast(unsigned short, (_Float16)hi);
  return (unsigned)l | ((unsigned)h << 16);
}

struct c2 { float x, y; };
__device__ __forceinline__ c2 cmul(c2 a, c2 b){ return c2{a.x*b.x - a.y*b.y, a.x*b.y + a.y*b.x}; }
__device__ __forceinline__ c2 cadd(c2 a, c2 b){ return c2{a.x+b.x, a.y+b.y}; }

__device__ __forceinline__ void rot2(c2 &a, c2 &b, c2 g00, c2 g01, c2 g10, c2 g11) {
  c2 na = cadd(cmul(g00,a), cmul(g01,b));
  c2 nb = cadd(cmul(g10,a), cmul(g11,b));
  a = na; b = nb;
}

__device__ __forceinline__ void mk_u3(float th, float ph, float la,
                                      c2 &g00, c2 &g01, c2 &g10, c2 &g11) {
  float ch = cosf(0.5f*th), sh = sinf(0.5f*th);
  float cl = cosf(la), sl = sinf(la);
  float cp = cosf(ph), sp = sinf(ph);
  float cpl = cp*cl - sp*sl, spl = sp*cl + cp*sl;
  g00 = c2{ch, 0.f};
  g01 = c2{-cl*sh, -sl*sh};
  g10 = c2{cp*sh, sp*sh};
  g11 = c2{cpl*ch, spl*ch};
}

template<int MA, int MB>
__device__ __forceinline__ void apply2q(c2 psi[16], const c2 M[16]) {
#pragma unroll
  for (int r = 0; r < 16; ++r) {
    if (r & (MA | MB)) continue;
    c2 a = psi[r], b = psi[r|MB], c = psi[r|MA], d = psi[r|MA|MB];
    psi[r]        = cadd(cadd(cmul(M[0],a),  cmul(M[1],b)),  cadd(cmul(M[2],c),  cmul(M[3],d)));
    psi[r|MB]     = cadd(cadd(cmul(M[4],a),  cmul(M[5],b)),  cadd(cmul(M[6],c),  cmul(M[7],d)));
    psi[r|MA]     = cadd(cadd(cmul(M[8],a),  cmul(M[9],b)),  cadd(cmul(M[10],c), cmul(M[11],d)));
    psi[r|MA|MB]  = cadd(cadd(cmul(M[12],a), cmul(M[13],b)), cadd(cmul(M[14],c), cmul(M[15],d)));
  }
}

// ---------------- K0: build A_w = Re(U^dag Z_w U), 4 x 16 x 16 ----------------
__global__ __launch_bounds__(256) void k_qmat(const float* __restrict__ qw_u3,
                                              const float* __restrict__ qw_ang,
                                              float* __restrict__ A) {
  __shared__ c2 SU[2][16];
  __shared__ float Ur[16*17], Ui[16*17];
  int t = threadIdx.x;
  if (t < 8) {
    int L = t >> 2, col = t & 3;
    c2 s[4];
#pragma unroll
    for (int i = 0; i < 4; ++i) s[i] = c2{(i==col)?1.f:0.f, 0.f};
    const float* u = qw_u3 + 12*L;
    const float* g = qw_ang + 3*L;
    c2 g00,g01,g10,g11;
    mk_u3(u[0],u[1],u[2], g00,g01,g10,g11);             // u3s[0] on a (mask 2)
    rot2(s[0],s[2], g00,g01,g10,g11); rot2(s[1],s[3], g00,g01,g10,g11);
    mk_u3(u[3],u[4],u[5], g00,g01,g10,g11);             // u3s[1] on b (mask 1)
    rot2(s[0],s[1], g00,g01,g10,g11); rot2(s[2],s[3], g00,g01,g10,g11);
    { c2 tmp = s[2]; s[2] = s[3]; s[3] = tmp; }          // CNOT a->b
    { float c = cosf(0.5f*g[0]), sn = sinf(0.5f*g[0]);
      c2 r00{c,0.f}, r01{-sn,0.f}, r10{sn,0.f}, r11{c,0.f};
      rot2(s[0],s[2], r00,r01,r10,r11); rot2(s[1],s[3], r00,r01,r10,r11); } // RY on a
    { float c = cosf(0.5f*g[1]), sn = sinf(0.5f*g[1]);
      c2 e0{c,-sn}, e1{c,sn};
      s[0]=cmul(s[0],e0); s[1]=cmul(s[1],e1); s[2]=cmul(s[2],e0); s[3]=cmul(s[3],e1); } // RZ on b
    { c2 tmp = s[1]; s[1] = s[3]; s[3] = tmp; }          // CNOT b->a
    { float c = cosf(0.5f*g[2]), sn = sinf(0.5f*g[2]);
      c2 r00{c,0.f}, r01{-sn,0.f}, r10{sn,0.f}, r11{c,0.f};
      rot2(s[0],s[2], r00,r01,r10,r11); rot2(s[1],s[3], r00,r01,r10,r11); } // RY on a
    { c2 tmp = s[2]; s[2] = s[3]; s[3] = tmp; }          // CNOT a->b
    mk_u3(u[6],u[7],u[8], g00,g01,g10,g11);             // u3s[2] on a
    rot2(s[0],s[2], g00,g01,g10,g11); rot2(s[1],s[3], g00,g01,g10,g11);
    mk_u3(u[9],u[10],u[11], g00,g01,g10,g11);           // u3s[3] on b
    rot2(s[0],s[1], g00,g01,g10,g11); rot2(s[2],s[3], g00,g01,g10,g11);
#pragma unroll
    for (int k = 0; k < 4; ++k) SU[L][k*4 + col] = s[k];
  }
  __syncthreads();
  if (t < 16) {
    c2 psi[16];
#pragma unroll
    for (int i = 0; i < 16; ++i) psi[i] = c2{(i==t)?1.f:0.f, 0.f};
#pragma unroll
    for (int l = 0; l < 2; ++l) {
      c2 M[16];
#pragma unroll
      for (int k = 0; k < 16; ++k) M[k] = SU[l][k];
      apply2q<8,4>(psi, M);   // pair (0,1)
      apply2q<4,2>(psi, M);   // pair (1,2)
      apply2q<2,1>(psi, M);   // pair (2,3)
      apply2q<1,8>(psi, M);   // pair (3,0)
    }
#pragma unroll
    for (int k = 0; k < 16; ++k) { Ur[k*17+t] = psi[k].x; Ui[k*17+t] = psi[k].y; }
  }
  __syncthreads();
  {
    int i = t >> 4, j = t & 15;
    float a0=0.f,a1=0.f,a2=0.f,a3=0.f;
#pragma unroll
    for (int k = 0; k < 16; ++k) {
      float pr = Ur[k*17+i]*Ur[k*17+j] + Ui[k*17+i]*Ui[k*17+j];
      a0 += ((k>>3)&1) ? -pr : pr;
      a1 += ((k>>2)&1) ? -pr : pr;
      a2 += ((k>>1)&1) ? -pr : pr;
      a3 += ( k     &1) ? -pr : pr;
    }
    A[0*256 + t] = a0; A[1*256 + t] = a1; A[2*256 + t] = a2; A[3*256 + t] = a3;
  }
}

// ------- Ktrans: FC transposes + conv2 MFMA B-frags + conv1 MFMA B-frags -------
// Bg (conv2): [18 slices][64 lanes][4 u32]; slice s: tap=s>>1, h=s&1.
//   Lane l: oc=l&15, j=l>>4. Reg r: lo = w2[oc][16h+4j+r][tap], hi = +32 ic.
// B1g (conv1): [4 nt][64 lanes][4 u32]; lane l: oc=nt*16+(l&15), j=l>>4.
//   Reg r: f16 pair (k=8j+2r, 8j+2r+1), flat k=c*9+tap, k>=27 -> 0.
__global__ __launch_bounds__(256) void k_trans(const float* __restrict__ w1a, const float* __restrict__ w1b,
                                               const float* __restrict__ w2a, const float* __restrict__ w2b,
                                               const float* __restrict__ c2w,
                                               const float* __restrict__ c1w, const float* __restrict__ c1b,
                                               float* __restrict__ wt) {
  int id = blockIdx.x*256 + threadIdx.x;
  if (id < 16384) { int j = id >> 6, o = id & 63;  wt[id] = w1a[o*256 + j]; return; }
  int id1 = id - 16384;
  if (id1 < 8192)  { int j = id1 >> 7, o = id1 & 127; wt[16384 + id1] = w1b[o*64 + j]; return; }
  int id2 = id1 - 8192;
  if (id2 < 8192)  { int j = id2 >> 6, o = id2 & 63;  wt[24576 + id2] = w2a[o*128 + j]; return; }
  int id3 = id2 - 8192;
  if (id3 < 640)   { int j = id3 / 10, o = id3 % 10;  wt[32768 + id3] = w2b[o*64 + j]; return; }
  int id4 = id3 - 640;
  if (id4 < 4608) {
    int s = id4 >> 8, rem = id4 & 255, l = rem >> 2, r = rem & 3;
    int tap = s >> 1, h = s & 1;
    int oc = l & 15, j = l >> 4;
    int icl = 16*h + 4*j + r;
    float lo = c2w[oc*576 + icl*9 + tap];
    float hi = c2w[oc*576 + (icl+32)*9 + tap];
    ((unsigned*)wt)[33408 + id4] = packh2(lo, hi);
    return;
  }
  int id5 = id4 - 4608;
  if (id5 < 1024) {
    int nt = id5 >> 8, rem = id5 & 255, l = rem >> 2, r = rem & 3;
    int oc = nt*16 + (l & 15), j = l >> 4;
    int k0 = 8*j + 2*r;
    float lo = (k0     < 27) ? c1w[oc*27 + k0]     : 0.f;
    float hi = (k0 + 1 < 27) ? c1w[oc*27 + k0 + 1] : 0.f;
    ((unsigned*)wt)[38016 + id5] = packh2(lo, hi);
  }
}

// ---- K1: conv1(3->64)+relu+pool, v4: implicit-GEMM via MFMA 16x16x32 f16. ----
// Block (b, h): half-image rows 16h..16h+15. M=512 pos, N=64 oc, K=27->32,
// flat k = c*9 + 3*wr + wc. im2col LDS [512 pos][20 u32] (stride 20 -> b128
// A-reads 16B-aligned, 2 lanes/bank = free). Thread t: builds positions
// (y=t>>4, x=2*(t&15)+{0,1}). Waves: w covers rows 4w..4w+3 in 2 passes of
// 2 rows; per pass 4 M-tiles x 4 N-tiles = 16 MFMA. Pool: x = in-lane reg
// pairs, y = tile pairs. h1p pairs (oc, oc+32) from N-tile pairs (nt, nt+2).
__global__ __launch_bounds__(256, 2) void k_conv1(const float* __restrict__ x,
                                                  const uint4* __restrict__ B1g,
                                                  const float* __restrict__ bias,
                                                  unsigned* __restrict__ h1p) {
  __shared__ float xs[3*18*34];        // 7344 B, padded cols (0 and 33 zero)
  __shared__ unsigned im2[512*20];     // 40960 B
  int bid = blockIdx.x, b = bid >> 1, h = bid & 1, t = threadIdx.x;
  int l = t & 63, w = t >> 6;
  int m = l & 15, j = l >> 4;
  // preload B fragments + bias (L2-resident, coalesced)
  uint4 Bf[4];
#pragma unroll
  for (int nt = 0; nt < 4; ++nt) Bf[nt] = B1g[nt*64 + l];
  float bz[4];
#pragma unroll
  for (int nt = 0; nt < 4; ++nt) bz[nt] = bias[nt*16 + m];
  for (int i = t; i < 1836; i += 256) xs[i] = 0.f;
  __syncthreads();
  // stage 18 rows (global rows 16h-1 .. 16h+16, clamped) coalesced
  for (int i = t; i < 1728; i += 256) {
    int c = i / 576, rem = i - c*576;
    int r = rem >> 5, ix = rem & 31;
    int gy = h*16 - 1 + r;
    if ((unsigned)gy < 32u)
      xs[c*612 + r*34 + 1 + ix] = x[(size_t)b*3072 + c*1024 + gy*32 + ix];
  }
  __syncthreads();
  // im2col: thread's 2 positions
  {
    int y = t >> 4, xp = t & 15;
    float win[3][3][4];
#pragma unroll
    for (int c = 0; c < 3; ++c)
#pragma unroll
      for (int wr = 0; wr < 3; ++wr) {
        float2 p0 = *(const float2*)&xs[c*612 + (y+wr)*34 + 2*xp];
        float2 p1 = *(const float2*)&xs[c*612 + (y+wr)*34 + 2*xp + 2];
        win[c][wr][0] = p0.x; win[c][wr][1] = p0.y;
        win[c][wr][2] = p1.x; win[c][wr][3] = p1.y;
      }
#pragma unroll
    for (int q = 0; q < 2; ++q) {
      int pos = y*32 + 2*xp + q;
      unsigned* dp = &im2[pos*20];
#pragma unroll
      for (int s4 = 0; s4 < 4; ++s4) {
        unsigned sl[4];
#pragma unroll
        for (int r2 = 0; r2 < 4; ++r2) {
          int k0 = 8*s4 + 2*r2, k1 = k0 + 1;
          float v0 = 0.f, v1 = 0.f;
          if (k0 < 27) { int c = k0/9, rr = (k0%9)/3, cc = k0%3; v0 = win[c][rr][cc+q]; }
          if (k1 < 27) { int c = k1/9, rr = (k1%9)/3, cc = k1%3; v1 = win[c][rr][cc+q]; }
          sl[r2] = packh2(v0, v1);
        }
        *(uint4*)(dp + 4*s4) = make_uint4(sl[0], sl[1], sl[2], sl[3]);
      }
    }
  }
  __syncthreads();
  unsigned* outb = h1p + (size_t)b*8192;
#pragma unroll
  for (int p = 0; p < 2; ++p) {
    f32x4v acc[2][2][4];                 // [row rr][xh][nt]
#pragma unroll
    for (int rr = 0; rr < 2; ++rr)
#pragma unroll
      for (int xh = 0; xh < 2; ++xh)
#pragma unroll
        for (int nt = 0; nt < 4; ++nt)
          acc[rr][xh][nt] = f32x4v{bz[nt], bz[nt], bz[nt], bz[nt]};
#pragma unroll
    for (int rr = 0; rr < 2; ++rr)
#pragma unroll
      for (int xh = 0; xh < 2; ++xh) {
        int pos = (4*w + 2*p + rr)*32 + 16*xh + m;
        f16x8 Av = __builtin_bit_cast(f16x8, *(const uint4*)&im2[pos*20 + 4*j]);
#pragma unroll
        for (int nt = 0; nt < 4; ++nt)
          acc[rr][xh][nt] = __builtin_amdgcn_mfma_f32_16x16x32_f16(
              Av, __builtin_bit_cast(f16x8, Bf[nt]), acc[rr][xh][nt], 0, 0, 0);
      }
    // pool + pack + write
    int pyg = h*8 + 2*w + p;
#pragma unroll
    for (int ntp = 0; ntp < 2; ++ntp)
#pragma unroll
      for (int xh = 0; xh < 2; ++xh)
#pragma unroll
        for (int pv = 0; pv < 2; ++pv) {
          f32x4v aL0 = acc[0][xh][ntp],   aL1 = acc[1][xh][ntp];
          f32x4v aH0 = acc[0][xh][ntp+2], aH1 = acc[1][xh][ntp+2];
          float mlo = fmaxf(fmaxf(aL0[2*pv], aL0[2*pv+1]), fmaxf(aL1[2*pv], aL1[2*pv+1]));
          float mhi = fmaxf(fmaxf(aH0[2*pv], aH0[2*pv+1]), fmaxf(aH1[2*pv], aH1[2*pv+1]));
          int px = 8*xh + 2*j + pv;
          outb[(ntp*16 + m)*256 + pyg*16 + px] = packh2(fmaxf(mlo, 0.f), fmaxf(mhi, 0.f));
        }
  }
}

// ---- K2: conv2(64->16)+relu+pool, v10: implicit-GEMM via MFMA 16x16x32 f16. ----
__global__ __launch_bounds__(256) void k_conv2(const unsigned* __restrict__ h1p,
                                               const uint4* __restrict__ Bg,
                                               const float* __restrict__ bias, float* __restrict__ h2) {
  __shared__ unsigned hsp[18*18*36];   // 11664 u32 = 46656 B
  int b = blockIdx.x, t = threadIdx.x;
  {
    uint4 z = make_uint4(0u,0u,0u,0u);
    uint4* hz = (uint4*)hsp;
    for (int i = t; i < 2916; i += 256) hz[i] = z;
  }
  int l = t & 63, w = t >> 6;
  int xcol = l & 15, j = l >> 4;
  uint4 Bf[18];
#pragma unroll
  for (int s = 0; s < 18; ++s) Bf[s] = Bg[s*64 + l];
  __syncthreads();
  {
    const unsigned* src = h1p + (size_t)b*8192;
    int ry = t >> 4, rx = t & 15;
    unsigned* dp = &hsp[((ry+1)*18 + rx+1)*36];
#pragma unroll
    for (int k = 0; k < 8; ++k) {
      unsigned q0 = src[(4*k+0)*256 + t];
      unsigned q1 = src[(4*k+1)*256 + t];
      unsigned q2 = src[(4*k+2)*256 + t];
      unsigned q3 = src[(4*k+3)*256 + t];
      *(uint4*)(dp + 4*k) = make_uint4(q0, q1, q2, q3);
    }
  }
  __syncthreads();
  float bz = bias[xcol];
  f32x4v acc[4];
#pragma unroll
  for (int tt = 0; tt < 4; ++tt) acc[tt] = f32x4v{bz, bz, bz, bz};
#pragma unroll
  for (int s = 0; s < 18; ++s) {
    const int tap = s >> 1, h = s & 1;
    const int dy = tap / 3, dx = tap % 3;
    f16x8 Bv = __builtin_bit_cast(f16x8, Bf[s]);
#pragma unroll
    for (int tt = 0; tt < 4; ++tt) {
      int y = 4*w + tt;
      f16x8 Av = __builtin_bit_cast(f16x8,
          *(const uint4*)&hsp[((y+dy)*18 + xcol+dx)*36 + 16*h + 4*j]);
      acc[tt] = __builtin_amdgcn_mfma_f32_16x16x32_f16(Av, Bv, acc[tt], 0, 0, 0);
    }
  }
  float* outb = h2 + (size_t)b*1024 + xcol*64;
#pragma unroll
  for (int tp = 0; tp < 2; ++tp)
#pragma unroll
    for (int vp = 0; vp < 2; ++vp) {
      float m = fmaxf(fmaxf(acc[2*tp][2*vp], acc[2*tp][2*vp+1]),
                      fmaxf(acc[2*tp+1][2*vp], acc[2*tp+1][2*vp+1]));
      int py = 2*w + tp, px = 2*j + vp;
      outb[py*8 + px] = fmaxf(m, 0.f);
    }
}

// ---- Ktail: conv3(16->4)+leaky+sigmoid*pi -> quantum forms -> full FC chain ----
__global__ __launch_bounds__(256) void k_tail(const float* __restrict__ h2, const float* __restrict__ w,
                                              const float* __restrict__ bias, const float* __restrict__ Ag,
                                              const float* __restrict__ wt,
                                              const float* __restrict__ b1a, const float* __restrict__ b1b,
                                              const float* __restrict__ b2a, const float* __restrict__ b2b,
                                              float* __restrict__ out) {
  __shared__ float S[8448];
  float* h3s = S;                      // [4][16][10][10] = 6400 (overlaid by fc S later)
  float* qs  = S + 6400;               // [4][256] = 1024
  float* As  = S + 7424;               // [4][256] = 1024
  int b4 = blockIdx.x*4, t = threadIdx.x;
#pragma unroll
  for (int k = 0; k < 4; ++k) As[t + k*256] = Ag[t + k*256];
  for (int i = t; i < 6400; i += 256) h3s[i] = 0.f;
  __syncthreads();
  int img = t >> 6, lane = t & 63;
  {
    const float4* src = (const float4*)(h2 + (size_t)(b4+img)*1024);
#pragma unroll
    for (int k = 0; k < 4; ++k) {
      float4 v = src[lane + k*64];
      int e = 4*(lane + k*64);
      int ic = e >> 6, iy = (e >> 3) & 7, ix = e & 7;
      float* d = &h3s[img*1600 + ic*100 + (iy+1)*10 + ix + 1];
      d[0]=v.x; d[1]=v.y; d[2]=v.z; d[3]=v.w;
    }
  }
  __syncthreads();
  {
    int y = lane >> 3, xo = lane & 7;
    float acc[4];
#pragma unroll
    for (int o = 0; o < 4; ++o) acc[o] = bias[o];
    for (int ic = 0; ic < 16; ++ic) {
      float in[3][3];
#pragma unroll
      for (int ky = 0; ky < 3; ++ky)
#pragma unroll
        for (int kx = 0; kx < 3; ++kx)
          in[ky][kx] = h3s[img*1600 + ic*100 + (y+ky)*10 + (xo+kx)];
#pragma unroll
      for (int o = 0; o < 4; ++o) {
        const float* wp = w + (o*16 + ic)*9;
#pragma unroll
        for (int ky = 0; ky < 3; ++ky)
#pragma unroll
          for (int kx = 0; kx < 3; ++kx)
            acc[o] = fmaf(wp[ky*3+kx], in[ky][kx], acc[o]);
      }
    }
    float v0[2], v1[2], v2[2], v3[2];
#pragma unroll
    for (int o = 0; o < 4; ++o) {
      float v = acc[o];
      float l = v > 0.f ? v : 0.01f*v;
      float sg = 1.f/(1.f + expf(-l));
      float sv, cv;
      __sincosf(sg * (0.5f*PI_F), &sv, &cv);
      float* dst = (o==0)?v0:(o==1)?v1:(o==2)?v2:v3;
      dst[0] = cv; dst[1] = sv;
    }
    float pv[16];
#pragma unroll
    for (int i = 0; i < 16; ++i)
      pv[i] = v0[(i>>3)&1] * v1[(i>>2)&1] * v2[(i>>1)&1] * v3[i&1];
#pragma unroll
    for (int w4 = 0; w4 < 4; ++w4) {
      const float4* Aw = (const float4*)(As + w4*256);
      float a = 0.f;
#pragma unroll
      for (int i = 0; i < 16; ++i) {
        float d = 0.f;
#pragma unroll
        for (int j4 = 0; j4 < 4; ++j4) {
          float4 av = Aw[i*4 + j4];
          d = fmaf(av.x, pv[j4*4+0], d);
          d = fmaf(av.y, pv[j4*4+1], d);
          d = fmaf(av.z, pv[j4*4+2], d);
          d = fmaf(av.w, pv[j4*4+3], d);
        }
        a = fmaf(pv[i], d, a);
      }
      qs[img*256 + lane*4 + w4] = a;
    }
  }
  __syncthreads();
  int wv = img;
  float* Sw = S + wv*512;
  ((float4*)Sw)[lane] = ((const float4*)(qs + wv*256))[lane];
  __syncthreads();
  const float* WT1a = wt;
  const float* WT1b = wt + 16384;
  const float* WT2a = wt + 24576;
  const float* WT2b = wt + 32768;
  float acc = b1a[lane];
  for (int j = 0; j < 256; ++j) acc = fmaf(WT1a[j*64+lane], Sw[j], acc);
  float hR = fmaxf(acc, 0.f);
  __syncthreads();
  Sw[256+lane] = hR;
  __syncthreads();
  float a0 = b1b[lane], a1 = b1b[64+lane];
  for (int j = 0; j < 64; ++j) {
    float sj = Sw[256+j];
    a0 = fmaf(WT1b[j*128+lane],    sj, a0);
    a1 = fmaf(WT1b[j*128+64+lane], sj, a1);
  }
  __syncthreads();
  Sw[320+lane] = a0; Sw[384+lane] = a1;
  __syncthreads();
  float c2a = b2a[lane];
  for (int j = 0; j < 128; ++j) c2a = fmaf(WT2a[j*64+lane], Sw[320+j], c2a);
  float h2v = fmaxf(c2a, 0.f);
  __syncthreads();
  Sw[448+lane] = h2v;
  __syncthreads();
  if (lane < 10) {
    float o = b2b[lane];
    for (int j = 0; j < 64; ++j) o = fmaf(WT2b[j*10+lane], Sw[448+j], o);
    out[(size_t)(b4+wv)*10 + lane] = o;
  }
}

extern "C" void kernel_launch(void* const* d_in, const int* in_sizes, int n_in,
                              void* d_out, int out_size, void* d_ws, size_t ws_size,
                              hipStream_t stream) {
  const float* x       = (const float*)d_in[0];
  const float* conv1_w = (const float*)d_in[1];
  const float* conv1_b = (const float*)d_in[2];
  const float* conv2_w = (const float*)d_in[3];
  const float* conv2_b = (const float*)d_in[4];
  const float* conv3_w = (const float*)d_in[5];
  const float* conv3_b = (const float*)d_in[6];
  const float* qw_u3   = (const float*)d_in[7];
  const float* qw_ang  = (const float*)d_in[8];
  const float* fc1a_w  = (const float*)d_in[9];
  const float* fc1a_b  = (const float*)d_in[10];
  const float* fc1b_w  = (const float*)d_in[11];
  const float* fc1b_b  = (const float*)d_in[12];
  const float* fc2a_w  = (const float*)d_in[13];
  const float* fc2a_b  = (const float*)d_in[14];
  const float* fc2b_w  = (const float*)d_in[15];
  const float* fc2b_b  = (const float*)d_in[16];
  float* out = (float*)d_out;

  float* ws  = (float*)d_ws;
  float* A   = ws;                      // 1024 floats
  float* WT  = ws + 1024;               // fc transposes (33408) + conv2 B (4608 u32) + conv1 B (1024 u32)
  const uint4* BG  = (const uint4*)((const unsigned*)WT + 33408);
  const uint4* B1G = (const uint4*)((const unsigned*)WT + 38016);
  unsigned* h1p = (unsigned*)(ws + 305792);  // 8388608 u32 (1024 x 32pair x 16 x 16)
  float* h2  = ws + 17083008;           // 1048576 floats  (1024x16x8x8)

  k_qmat  <<<1,    256, 0, stream>>>(qw_u3, qw_ang, A);
  k_trans <<<167,  256, 0, stream>>>(fc1a_w, fc1b_w, fc2a_w, fc2b_w, conv2_w, conv1_w, conv1_b, WT);
  k_conv1 <<<2048, 256, 0, stream>>>(x, B1G, conv1_b, h1p);
  k_conv2 <<<1024, 256, 0, stream>>>(h1p, BG, conv2_b, h2);
  k_tail  <<<256,  256, 0, stream>>>(h2, conv3_w, conv3_b, A, WT,
                                     fc1a_b, fc1b_b, fc2a_b, fc2b_b, out);
}

// Round 16
// 65.035 us; speedup vs baseline: 2.1246x; 1.2575x over previous
//
#include <hip/hip_runtime.h>
#include <math.h>

#define PI_F 3.14159265358979323846f

typedef _Float16 half2_t __attribute__((ext_vector_type(2)));
typedef _Float16 f16x8 __attribute__((ext_vector_type(8)));
typedef float f32x4v __attribute__((ext_vector_type(4)));

__device__ __forceinline__ unsigned packh2(float lo, float hi) {
  unsigned short l = __builtin_bit_cast(unsigned short, (_Float16)lo);
  unsigned short h = __builtin_bit_cast(unsigned short, (_Float16)hi);
  return (unsigned)l | ((unsigned)h << 16);
}

struct c2 { float x, y; };
__device__ __forceinline__ c2 cmul(c2 a, c2 b){ return c2{a.x*b.x - a.y*b.y, a.x*b.y + a.y*b.x}; }
__device__ __forceinline__ c2 cadd(c2 a, c2 b){ return c2{a.x+b.x, a.y+b.y}; }

__device__ __forceinline__ void rot2(c2 &a, c2 &b, c2 g00, c2 g01, c2 g10, c2 g11) {
  c2 na = cadd(cmul(g00,a), cmul(g01,b));
  c2 nb = cadd(cmul(g10,a), cmul(g11,b));
  a = na; b = nb;
}

__device__ __forceinline__ void mk_u3(float th, float ph, float la,
                                      c2 &g00, c2 &g01, c2 &g10, c2 &g11) {
  float ch = cosf(0.5f*th), sh = sinf(0.5f*th);
  float cl = cosf(la), sl = sinf(la);
  float cp = cosf(ph), sp = sinf(ph);
  float cpl = cp*cl - sp*sl, spl = sp*cl + cp*sl;
  g00 = c2{ch, 0.f};
  g01 = c2{-cl*sh, -sl*sh};
  g10 = c2{cp*sh, sp*sh};
  g11 = c2{cpl*ch, spl*ch};
}

template<int MA, int MB>
__device__ __forceinline__ void apply2q(c2 psi[16], const c2 M[16]) {
#pragma unroll
  for (int r = 0; r < 16; ++r) {
    if (r & (MA | MB)) continue;
    c2 a = psi[r], b = psi[r|MB], c = psi[r|MA], d = psi[r|MA|MB];
    psi[r]        = cadd(cadd(cmul(M[0],a),  cmul(M[1],b)),  cadd(cmul(M[2],c),  cmul(M[3],d)));
    psi[r|MB]     = cadd(cadd(cmul(M[4],a),  cmul(M[5],b)),  cadd(cmul(M[6],c),  cmul(M[7],d)));
    psi[r|MA]     = cadd(cadd(cmul(M[8],a),  cmul(M[9],b)),  cadd(cmul(M[10],c), cmul(M[11],d)));
    psi[r|MA|MB]  = cadd(cadd(cmul(M[12],a), cmul(M[13],b)), cadd(cmul(M[14],c), cmul(M[15],d)));
  }
}

// ---------------- K0: build A_w = Re(U^dag Z_w U), 4 x 16 x 16 ----------------
__global__ __launch_bounds__(256) void k_qmat(const float* __restrict__ qw_u3,
                                              const float* __restrict__ qw_ang,
                                              float* __restrict__ A) {
  __shared__ c2 SU[2][16];
  __shared__ float Ur[16*17], Ui[16*17];
  int t = threadIdx.x;
  if (t < 8) {
    int L = t >> 2, col = t & 3;
    c2 s[4];
#pragma unroll
    for (int i = 0; i < 4; ++i) s[i] = c2{(i==col)?1.f:0.f, 0.f};
    const float* u = qw_u3 + 12*L;
    const float* g = qw_ang + 3*L;
    c2 g00,g01,g10,g11;
    mk_u3(u[0],u[1],u[2], g00,g01,g10,g11);             // u3s[0] on a (mask 2)
    rot2(s[0],s[2], g00,g01,g10,g11); rot2(s[1],s[3], g00,g01,g10,g11);
    mk_u3(u[3],u[4],u[5], g00,g01,g10,g11);             // u3s[1] on b (mask 1)
    rot2(s[0],s[1], g00,g01,g10,g11); rot2(s[2],s[3], g00,g01,g10,g11);
    { c2 tmp = s[2]; s[2] = s[3]; s[3] = tmp; }          // CNOT a->b
    { float c = cosf(0.5f*g[0]), sn = sinf(0.5f*g[0]);
      c2 r00{c,0.f}, r01{-sn,0.f}, r10{sn,0.f}, r11{c,0.f};
      rot2(s[0],s[2], r00,r01,r10,r11); rot2(s[1],s[3], r00,r01,r10,r11); } // RY on a
    { float c = cosf(0.5f*g[1]), sn = sinf(0.5f*g[1]);
      c2 e0{c,-sn}, e1{c,sn};
      s[0]=cmul(s[0],e0); s[1]=cmul(s[1],e1); s[2]=cmul(s[2],e0); s[3]=cmul(s[3],e1); } // RZ on b
    { c2 tmp = s[1]; s[1] = s[3]; s[3] = tmp; }          // CNOT b->a
    { float c = cosf(0.5f*g[2]), sn = sinf(0.5f*g[2]);
      c2 r00{c,0.f}, r01{-sn,0.f}, r10{sn,0.f}, r11{c,0.f};
      rot2(s[0],s[2], r00,r01,r10,r11); rot2(s[1],s[3], r00,r01,r10,r11); } // RY on a
    { c2 tmp = s[2]; s[2] = s[3]; s[3] = tmp; }          // CNOT a->b
    mk_u3(u[6],u[7],u[8], g00,g01,g10,g11);             // u3s[2] on a
    rot2(s[0],s[2], g00,g01,g10,g11); rot2(s[1],s[3], g00,g01,g10,g11);
    mk_u3(u[9],u[10],u[11], g00,g01,g10,g11);           // u3s[3] on b
    rot2(s[0],s[1], g00,g01,g10,g11); rot2(s[2],s[3], g00,g01,g10,g11);
#pragma unroll
    for (int k = 0; k < 4; ++k) SU[L][k*4 + col] = s[k];
  }
  __syncthreads();
  if (t < 16) {
    c2 psi[16];
#pragma unroll
    for (int i = 0; i < 16; ++i) psi[i] = c2{(i==t)?1.f:0.f, 0.f};
#pragma unroll
    for (int l = 0; l < 2; ++l) {
      c2 M[16];
#pragma unroll
      for (int k = 0; k < 16; ++k) M[k] = SU[l][k];
      apply2q<8,4>(psi, M);   // pair (0,1)
      apply2q<4,2>(psi, M);   // pair (1,2)
      apply2q<2,1>(psi, M);   // pair (2,3)
      apply2q<1,8>(psi, M);   // pair (3,0)
    }
#pragma unroll
    for (int k = 0; k < 16; ++k) { Ur[k*17+t] = psi[k].x; Ui[k*17+t] = psi[k].y; }
  }
  __syncthreads();
  {
    int i = t >> 4, j = t & 15;
    float a0=0.f,a1=0.f,a2=0.f,a3=0.f;
#pragma unroll
    for (int k = 0; k < 16; ++k) {
      float pr = Ur[k*17+i]*Ur[k*17+j] + Ui[k*17+i]*Ui[k*17+j];
      a0 += ((k>>3)&1) ? -pr : pr;
      a1 += ((k>>2)&1) ? -pr : pr;
      a2 += ((k>>1)&1) ? -pr : pr;
      a3 += ( k     &1) ? -pr : pr;
    }
    A[0*256 + t] = a0; A[1*256 + t] = a1; A[2*256 + t] = a2; A[3*256 + t] = a3;
  }
}

// ------- Ktrans: FC transposes + conv2 MFMA B-frags + conv1 MFMA B-frags -------
// Bg (conv2): [18 slices][64 lanes][4 u32]; slice s: tap=s>>1, h=s&1.
//   Lane l: oc=l&15, j=l>>4. Reg r: lo = w2[oc][16h+4j+r][tap], hi = +32 ic.
// B1g (conv1): [4 nt][64 lanes][4 u32]; lane l: oc=nt*16+(l&15), j=l>>4.
//   Reg r: f16 pair (k=8j+2r, 8j+2r+1), flat k=c*9+tap, k>=27 -> 0.
__global__ __launch_bounds__(256) void k_trans(const float* __restrict__ w1a, const float* __restrict__ w1b,
                                               const float* __restrict__ w2a, const float* __restrict__ w2b,
                                               const float* __restrict__ c2w,
                                               const float* __restrict__ c1w, const float* __restrict__ c1b,
                                               float* __restrict__ wt) {
  int id = blockIdx.x*256 + threadIdx.x;
  if (id < 16384) { int j = id >> 6, o = id & 63;  wt[id] = w1a[o*256 + j]; return; }
  int id1 = id - 16384;
  if (id1 < 8192)  { int j = id1 >> 7, o = id1 & 127; wt[16384 + id1] = w1b[o*64 + j]; return; }
  int id2 = id1 - 8192;
  if (id2 < 8192)  { int j = id2 >> 6, o = id2 & 63;  wt[24576 + id2] = w2a[o*128 + j]; return; }
  int id3 = id2 - 8192;
  if (id3 < 640)   { int j = id3 / 10, o = id3 % 10;  wt[32768 + id3] = w2b[o*64 + j]; return; }
  int id4 = id3 - 640;
  if (id4 < 4608) {
    int s = id4 >> 8, rem = id4 & 255, l = rem >> 2, r = rem & 3;
    int tap = s >> 1, h = s & 1;
    int oc = l & 15, j = l >> 4;
    int icl = 16*h + 4*j + r;
    float lo = c2w[oc*576 + icl*9 + tap];
    float hi = c2w[oc*576 + (icl+32)*9 + tap];
    ((unsigned*)wt)[33408 + id4] = packh2(lo, hi);
    return;
  }
  int id5 = id4 - 4608;
  if (id5 < 1024) {
    int nt = id5 >> 8, rem = id5 & 255, l = rem >> 2, r = rem & 3;
    int oc = nt*16 + (l & 15), j = l >> 4;
    int k0 = 8*j + 2*r;
    float lo = (k0     < 27) ? c1w[oc*27 + k0]     : 0.f;
    float hi = (k0 + 1 < 27) ? c1w[oc*27 + k0 + 1] : 0.f;
    ((unsigned*)wt)[38016 + id5] = packh2(lo, hi);
  }
}

// ---- K12: FUSED conv1+pool -> conv2+pool, one image per block, 512 threads. ----
// Phase 1 (conv1, per half h): im2col [512 pos][20 u32] (stride 20 -> b128
//   reads 2 lanes/bank), 16 MFMA/wave; pooled+relu'd output packh2(oc,oc+32)
//   written DIRECTLY into conv2's staging layout hsp[18][18][36] (halo zeroed).
//   Write banks = (8j+m)%32 -> <=2-way.
// Phase 2 (conv2): identical to verified v10 but 8 waves x 2 row-tiles;
//   A-reads conflict-free, pool in-lane/tile-pairs, write h2.
// All MFMA layouts / pack order byte-identical to r15 -> bit-identical output.
__global__ __launch_bounds__(512, 2) void k_conv12(
    const float* __restrict__ x,
    const uint4* __restrict__ B1g, const float* __restrict__ b1,
    const uint4* __restrict__ B2g, const float* __restrict__ b2,
    float* __restrict__ h2) {
  __shared__ unsigned smem[25384];     // 101536 B
  float* xs = (float*)smem;            // [3][34][34] f32, stride 1156 (3468 used)
  unsigned* im2 = smem + 3480;         // [512][20] u32
  unsigned* hsp = smem + 13720;        // [18][18][36] u32
  int b = blockIdx.x, t = threadIdx.x;
  int l = t & 63, w = t >> 6;          // 8 waves
  int m = l & 15, j = l >> 4;
  // preload conv1 B-frags + bias
  uint4 Bf1[4];
#pragma unroll
  for (int nt = 0; nt < 4; ++nt) Bf1[nt] = B1g[nt*64 + l];
  float bz1[4];
#pragma unroll
  for (int nt = 0; nt < 4; ++nt) bz1[nt] = b1[nt*16 + m];
  // zero xs (padding) + hsp (halo)
  for (int i = t; i < 3480; i += 512) xs[i] = 0.f;
  {
    uint4 z = make_uint4(0u,0u,0u,0u);
    uint4* hz = (uint4*)hsp;
    for (int i = t; i < 2916; i += 512) hz[i] = z;
  }
  __syncthreads();
  // fill xs interior (coalesced)
  for (int i = t; i < 3072; i += 512) {
    int c = i >> 10, rem = i & 1023, gy = rem >> 5, gx = rem & 31;
    xs[c*1156 + (gy+1)*34 + gx + 1] = x[(size_t)b*3072 + i];
  }
  __syncthreads();
#pragma unroll
  for (int h = 0; h < 2; ++h) {
    // --- im2col: thread t builds position t of this half (k-linear, pairs (2s,2s+1)) ---
    {
      int yl = t >> 5, xq = t & 31;
      float win[27];
#pragma unroll
      for (int c = 0; c < 3; ++c)
#pragma unroll
        for (int wr = 0; wr < 3; ++wr)
#pragma unroll
          for (int cc = 0; cc < 3; ++cc)
            win[c*9 + wr*3 + cc] = xs[c*1156 + (16*h + yl + wr)*34 + xq + cc];
      unsigned* dp = im2 + t*20;
#pragma unroll
      for (int s4 = 0; s4 < 4; ++s4) {
        unsigned sl[4];
#pragma unroll
        for (int r = 0; r < 4; ++r) {
          int k0 = 8*s4 + 2*r;
          float v0 = (k0     < 27) ? win[k0]   : 0.f;
          float v1 = (k0 + 1 < 27) ? win[k0+1] : 0.f;
          sl[r] = packh2(v0, v1);
        }
        *(uint4*)(dp + 4*s4) = make_uint4(sl[0], sl[1], sl[2], sl[3]);
      }
    }
    __syncthreads();
    // --- conv1 MFMA: wave w = local rows {2w, 2w+1}; 4 M-tiles x 4 N-tiles ---
    f32x4v acc[2][2][4];
#pragma unroll
    for (int rr = 0; rr < 2; ++rr)
#pragma unroll
      for (int xh = 0; xh < 2; ++xh)
#pragma unroll
        for (int nt = 0; nt < 4; ++nt)
          acc[rr][xh][nt] = f32x4v{bz1[nt], bz1[nt], bz1[nt], bz1[nt]};
#pragma unroll
    for (int rr = 0; rr < 2; ++rr)
#pragma unroll
      for (int xh = 0; xh < 2; ++xh) {
        int pos = (2*w + rr)*32 + 16*xh + m;
        f16x8 Av = __builtin_bit_cast(f16x8, *(const uint4*)(im2 + pos*20 + 4*j));
#pragma unroll
        for (int nt = 0; nt < 4; ++nt)
          acc[rr][xh][nt] = __builtin_amdgcn_mfma_f32_16x16x32_f16(
              Av, __builtin_bit_cast(f16x8, Bf1[nt]), acc[rr][xh][nt], 0, 0, 0);
      }
    // --- pool 2x2 (y = rr pair, x = in-lane reg pairs) + relu + pack -> hsp ---
    {
      int pyg = 8*h + w;               // pooled row 0..15
#pragma unroll
      for (int ntp = 0; ntp < 2; ++ntp)
#pragma unroll
        for (int xh = 0; xh < 2; ++xh)
#pragma unroll
          for (int pv = 0; pv < 2; ++pv) {
            f32x4v aL0 = acc[0][xh][ntp],   aL1 = acc[1][xh][ntp];
            f32x4v aH0 = acc[0][xh][ntp+2], aH1 = acc[1][xh][ntp+2];
            float mlo = fmaxf(fmaxf(aL0[2*pv], aL0[2*pv+1]), fmaxf(aL1[2*pv], aL1[2*pv+1]));
            float mhi = fmaxf(fmaxf(aH0[2*pv], aH0[2*pv+1]), fmaxf(aH1[2*pv], aH1[2*pv+1]));
            int px = 8*xh + 2*j + pv;  // pooled col 0..15
            hsp[((pyg+1)*18 + px + 1)*36 + ntp*16 + m] =
                packh2(fmaxf(mlo, 0.f), fmaxf(mhi, 0.f));
          }
    }
    __syncthreads();                   // im2 reuse next half / hsp complete
  }
  // --- conv2 phase (v10 layout, 8 waves x 2 row-tiles) ---
  uint4 Bf2[18];
#pragma unroll
  for (int s = 0; s < 18; ++s) Bf2[s] = B2g[s*64 + l];
  float bz2 = b2[m];
  f32x4v a2[2];
  a2[0] = f32x4v{bz2, bz2, bz2, bz2};
  a2[1] = f32x4v{bz2, bz2, bz2, bz2};
#pragma unroll
  for (int s = 0; s < 18; ++s) {
    const int tap = s >> 1, hh = s & 1;
    const int dy = tap / 3, dx = tap % 3;
    f16x8 Bv = __builtin_bit_cast(f16x8, Bf2[s]);
#pragma unroll
    for (int tt = 0; tt < 2; ++tt) {
      int y = 2*w + tt;
      f16x8 Av = __builtin_bit_cast(f16x8,
          *(const uint4*)(hsp + ((y+dy)*18 + m + dx)*36 + 16*hh + 4*j));
      a2[tt] = __builtin_amdgcn_mfma_f32_16x16x32_f16(Av, Bv, a2[tt], 0, 0, 0);
    }
  }
  float* outb = h2 + (size_t)b*1024 + m*64;
#pragma unroll
  for (int vp = 0; vp < 2; ++vp) {
    float mm = fmaxf(fmaxf(a2[0][2*vp], a2[0][2*vp+1]),
                     fmaxf(a2[1][2*vp], a2[1][2*vp+1]));
    outb[w*8 + 2*j + vp] = fmaxf(mm, 0.f);
  }
}

// ---- Ktail: conv3(16->4)+leaky+sigmoid*pi -> quantum forms -> full FC chain ----
__global__ __launch_bounds__(256) void k_tail(const float* __restrict__ h2, const float* __restrict__ w,
                                              const float* __restrict__ bias, const float* __restrict__ Ag,
                                              const float* __restrict__ wt,
                                              const float* __restrict__ b1a, const float* __restrict__ b1b,
                                              const float* __restrict__ b2a, const float* __restrict__ b2b,
                                              float* __restrict__ out) {
  __shared__ float S[8448];
  float* h3s = S;                      // [4][16][10][10] = 6400 (overlaid by fc S later)
  float* qs  = S + 6400;               // [4][256] = 1024
  float* As  = S + 7424;               // [4][256] = 1024
  int b4 = blockIdx.x*4, t = threadIdx.x;
#pragma unroll
  for (int k = 0; k < 4; ++k) As[t + k*256] = Ag[t + k*256];
  for (int i = t; i < 6400; i += 256) h3s[i] = 0.f;
  __syncthreads();
  int img = t >> 6, lane = t & 63;
  {
    const float4* src = (const float4*)(h2 + (size_t)(b4+img)*1024);
#pragma unroll
    for (int k = 0; k < 4; ++k) {
      float4 v = src[lane + k*64];
      int e = 4*(lane + k*64);
      int ic = e >> 6, iy = (e >> 3) & 7, ix = e & 7;
      float* d = &h3s[img*1600 + ic*100 + (iy+1)*10 + ix + 1];
      d[0]=v.x; d[1]=v.y; d[2]=v.z; d[3]=v.w;
    }
  }
  __syncthreads();
  {
    int y = lane >> 3, xo = lane & 7;
    float acc[4];
#pragma unroll
    for (int o = 0; o < 4; ++o) acc[o] = bias[o];
    for (int ic = 0; ic < 16; ++ic) {
      float in[3][3];
#pragma unroll
      for (int ky = 0; ky < 3; ++ky)
#pragma unroll
        for (int kx = 0; kx < 3; ++kx)
          in[ky][kx] = h3s[img*1600 + ic*100 + (y+ky)*10 + (xo+kx)];
#pragma unroll
      for (int o = 0; o < 4; ++o) {
        const float* wp = w + (o*16 + ic)*9;
#pragma unroll
        for (int ky = 0; ky < 3; ++ky)
#pragma unroll
          for (int kx = 0; kx < 3; ++kx)
            acc[o] = fmaf(wp[ky*3+kx], in[ky][kx], acc[o]);
      }
    }
    float v0[2], v1[2], v2[2], v3[2];
#pragma unroll
    for (int o = 0; o < 4; ++o) {
      float v = acc[o];
      float l = v > 0.f ? v : 0.01f*v;
      float sg = 1.f/(1.f + expf(-l));
      float sv, cv;
      __sincosf(sg * (0.5f*PI_F), &sv, &cv);
      float* dst = (o==0)?v0:(o==1)?v1:(o==2)?v2:v3;
      dst[0] = cv; dst[1] = sv;
    }
    float pv[16];
#pragma unroll
    for (int i = 0; i < 16; ++i)
      pv[i] = v0[(i>>3)&1] * v1[(i>>2)&1] * v2[(i>>1)&1] * v3[i&1];
#pragma unroll
    for (int w4 = 0; w4 < 4; ++w4) {
      const float4* Aw = (const float4*)(As + w4*256);
      float a = 0.f;
#pragma unroll
      for (int i = 0; i < 16; ++i) {
        float d = 0.f;
#pragma unroll
        for (int j4 = 0; j4 < 4; ++j4) {
          float4 av = Aw[i*4 + j4];
          d = fmaf(av.x, pv[j4*4+0], d);
          d = fmaf(av.y, pv[j4*4+1], d);
          d = fmaf(av.z, pv[j4*4+2], d);
          d = fmaf(av.w, pv[j4*4+3], d);
        }
        a = fmaf(pv[i], d, a);
      }
      qs[img*256 + lane*4 + w4] = a;
    }
  }
  __syncthreads();
  int wv = img;
  float* Sw = S + wv*512;
  ((float4*)Sw)[lane] = ((const float4*)(qs + wv*256))[lane];
  __syncthreads();
  const float* WT1a = wt;
  const float* WT1b = wt + 16384;
  const float* WT2a = wt + 24576;
  const float* WT2b = wt + 32768;
  float acc = b1a[lane];
  for (int j = 0; j < 256; ++j) acc = fmaf(WT1a[j*64+lane], Sw[j], acc);
  float hR = fmaxf(acc, 0.f);
  __syncthreads();
  Sw[256+lane] = hR;
  __syncthreads();
  float a0 = b1b[lane], a1 = b1b[64+lane];
  for (int j = 0; j < 64; ++j) {
    float sj = Sw[256+j];
    a0 = fmaf(WT1b[j*128+lane],    sj, a0);
    a1 = fmaf(WT1b[j*128+64+lane], sj, a1);
  }
  __syncthreads();
  Sw[320+lane] = a0; Sw[384+lane] = a1;
  __syncthreads();
  float c2a = b2a[lane];
  for (int j = 0; j < 128; ++j) c2a = fmaf(WT2a[j*64+lane], Sw[320+j], c2a);
  float h2v = fmaxf(c2a, 0.f);
  __syncthreads();
  Sw[448+lane] = h2v;
  __syncthreads();
  if (lane < 10) {
    float o = b2b[lane];
    for (int j = 0; j < 64; ++j) o = fmaf(WT2b[j*10+lane], Sw[448+j], o);
    out[(size_t)(b4+wv)*10 + lane] = o;
  }
}

extern "C" void kernel_launch(void* const* d_in, const int* in_sizes, int n_in,
                              void* d_out, int out_size, void* d_ws, size_t ws_size,
                              hipStream_t stream) {
  const float* x       = (const float*)d_in[0];
  const float* conv1_w = (const float*)d_in[1];
  const float* conv1_b = (const float*)d_in[2];
  const float* conv2_w = (const float*)d_in[3];
  const float* conv2_b = (const float*)d_in[4];
  const float* conv3_w = (const float*)d_in[5];
  const float* conv3_b = (const float*)d_in[6];
  const float* qw_u3   = (const float*)d_in[7];
  const float* qw_ang  = (const float*)d_in[8];
  const float* fc1a_w  = (const float*)d_in[9];
  const float* fc1a_b  = (const float*)d_in[10];
  const float* fc1b_w  = (const float*)d_in[11];
  const float* fc1b_b  = (const float*)d_in[12];
  const float* fc2a_w  = (const float*)d_in[13];
  const float* fc2a_b  = (const float*)d_in[14];
  const float* fc2b_w  = (const float*)d_in[15];
  const float* fc2b_b  = (const float*)d_in[16];
  float* out = (float*)d_out;

  float* ws  = (float*)d_ws;
  float* A   = ws;                      // 1024 floats
  float* WT  = ws + 1024;               // fc transposes (33408) + conv2 B (4608 u32) + conv1 B (1024 u32)
  const uint4* BG  = (const uint4*)((const unsigned*)WT + 33408);
  const uint4* B1G = (const uint4*)((const unsigned*)WT + 38016);
  float* h2  = ws + 17083008;           // 1048576 floats (1024x16x8x8)

  k_qmat  <<<1,    256, 0, stream>>>(qw_u3, qw_ang, A);
  k_trans <<<167,  256, 0, stream>>>(fc1a_w, fc1b_w, fc2a_w, fc2b_w, conv2_w, conv1_w, conv1_b, WT);
  k_conv12<<<1024, 512, 0, stream>>>(x, B1G, conv1_b, BG, conv2_b, h2);
  k_tail  <<<256,  256, 0, stream>>>(h2, conv3_w, conv3_b, A, WT,
                                     fc1a_b, fc1b_b, fc2a_b, fc2b_b, out);
}

// Round 17
// 58.145 us; speedup vs baseline: 2.3764x; 1.1185x over previous
//
#include <hip/hip_runtime.h>
#include <math.h>

#define PI_F 3.14159265358979323846f

typedef _Float16 half2_t __attribute__((ext_vector_type(2)));
typedef _Float16 f16x8 __attribute__((ext_vector_type(8)));
typedef float f32x4v __attribute__((ext_vector_type(4)));

__device__ __forceinline__ unsigned packh2(float lo, float hi) {
  unsigned short l = __builtin_bit_cast(unsigned short, (_Float16)lo);
  unsigned short h = __builtin_bit_cast(unsigned short, (_Float16)hi);
  return (unsigned)l | ((unsigned)h << 16);
}

struct c2 { float x, y; };
__device__ __forceinline__ c2 cmul(c2 a, c2 b){ return c2{a.x*b.x - a.y*b.y, a.x*b.y + a.y*b.x}; }
__device__ __forceinline__ c2 cadd(c2 a, c2 b){ return c2{a.x+b.x, a.y+b.y}; }

__device__ __forceinline__ void rot2(c2 &a, c2 &b, c2 g00, c2 g01, c2 g10, c2 g11) {
  c2 na = cadd(cmul(g00,a), cmul(g01,b));
  c2 nb = cadd(cmul(g10,a), cmul(g11,b));
  a = na; b = nb;
}

__device__ __forceinline__ void mk_u3(float th, float ph, float la,
                                      c2 &g00, c2 &g01, c2 &g10, c2 &g11) {
  float ch = cosf(0.5f*th), sh = sinf(0.5f*th);
  float cl = cosf(la), sl = sinf(la);
  float cp = cosf(ph), sp = sinf(ph);
  float cpl = cp*cl - sp*sl, spl = sp*cl + cp*sl;
  g00 = c2{ch, 0.f};
  g01 = c2{-cl*sh, -sl*sh};
  g10 = c2{cp*sh, sp*sh};
  g11 = c2{cpl*ch, spl*ch};
}

template<int MA, int MB>
__device__ __forceinline__ void apply2q(c2 psi[16], const c2 M[16]) {
#pragma unroll
  for (int r = 0; r < 16; ++r) {
    if (r & (MA | MB)) continue;
    c2 a = psi[r], b = psi[r|MB], c = psi[r|MA], d = psi[r|MA|MB];
    psi[r]        = cadd(cadd(cmul(M[0],a),  cmul(M[1],b)),  cadd(cmul(M[2],c),  cmul(M[3],d)));
    psi[r|MB]     = cadd(cadd(cmul(M[4],a),  cmul(M[5],b)),  cadd(cmul(M[6],c),  cmul(M[7],d)));
    psi[r|MA]     = cadd(cadd(cmul(M[8],a),  cmul(M[9],b)),  cadd(cmul(M[10],c), cmul(M[11],d)));
    psi[r|MA|MB]  = cadd(cadd(cmul(M[12],a), cmul(M[13],b)), cadd(cmul(M[14],c), cmul(M[15],d)));
  }
}

// ------- Ksetup: blocks 0..166 = weight transposes/packs; block 167 = qmat. -------
// Bg (conv2): [18 slices][64 lanes][4 u32]; slice s: tap=s>>1, h=s&1.
//   Lane l: oc=l&15, j=l>>4. Reg r: lo = w2[oc][16h+4j+r][tap], hi = +32 ic.
// B1g (conv1): [4 nt][64 lanes][4 u32]; lane l: oc=nt*16+(l&15), j=l>>4.
//   Reg r: f16 pair (k=8j+2r, 8j+2r+1), flat k=c*9+tap, k>=27 -> 0.
__global__ __launch_bounds__(256) void k_setup(const float* __restrict__ w1a, const float* __restrict__ w1b,
                                               const float* __restrict__ w2a, const float* __restrict__ w2b,
                                               const float* __restrict__ c2w,
                                               const float* __restrict__ c1w, const float* __restrict__ c1b,
                                               const float* __restrict__ qw_u3,
                                               const float* __restrict__ qw_ang,
                                               float* __restrict__ wt, float* __restrict__ A) {
  __shared__ c2 SU[2][16];
  __shared__ float Ur[16*17], Ui[16*17];
  int t = threadIdx.x;
  if (blockIdx.x == 167) {
    // ---------------- qmat: build A_w = Re(U^dag Z_w U) ----------------
    if (t < 8) {
      int L = t >> 2, col = t & 3;
      c2 s[4];
#pragma unroll
      for (int i = 0; i < 4; ++i) s[i] = c2{(i==col)?1.f:0.f, 0.f};
      const float* u = qw_u3 + 12*L;
      const float* g = qw_ang + 3*L;
      c2 g00,g01,g10,g11;
      mk_u3(u[0],u[1],u[2], g00,g01,g10,g11);
      rot2(s[0],s[2], g00,g01,g10,g11); rot2(s[1],s[3], g00,g01,g10,g11);
      mk_u3(u[3],u[4],u[5], g00,g01,g10,g11);
      rot2(s[0],s[1], g00,g01,g10,g11); rot2(s[2],s[3], g00,g01,g10,g11);
      { c2 tmp = s[2]; s[2] = s[3]; s[3] = tmp; }
      { float c = cosf(0.5f*g[0]), sn = sinf(0.5f*g[0]);
        c2 r00{c,0.f}, r01{-sn,0.f}, r10{sn,0.f}, r11{c,0.f};
        rot2(s[0],s[2], r00,r01,r10,r11); rot2(s[1],s[3], r00,r01,r10,r11); }
      { float c = cosf(0.5f*g[1]), sn = sinf(0.5f*g[1]);
        c2 e0{c,-sn}, e1{c,sn};
        s[0]=cmul(s[0],e0); s[1]=cmul(s[1],e1); s[2]=cmul(s[2],e0); s[3]=cmul(s[3],e1); }
      { c2 tmp = s[1]; s[1] = s[3]; s[3] = tmp; }
      { float c = cosf(0.5f*g[2]), sn = sinf(0.5f*g[2]);
        c2 r00{c,0.f}, r01{-sn,0.f}, r10{sn,0.f}, r11{c,0.f};
        rot2(s[0],s[2], r00,r01,r10,r11); rot2(s[1],s[3], r00,r01,r10,r11); }
      { c2 tmp = s[2]; s[2] = s[3]; s[3] = tmp; }
      mk_u3(u[6],u[7],u[8], g00,g01,g10,g11);
      rot2(s[0],s[2], g00,g01,g10,g11); rot2(s[1],s[3], g00,g01,g10,g11);
      mk_u3(u[9],u[10],u[11], g00,g01,g10,g11);
      rot2(s[0],s[1], g00,g01,g10,g11); rot2(s[2],s[3], g00,g01,g10,g11);
#pragma unroll
      for (int k = 0; k < 4; ++k) SU[L][k*4 + col] = s[k];
    }
    __syncthreads();
    if (t < 16) {
      c2 psi[16];
#pragma unroll
      for (int i = 0; i < 16; ++i) psi[i] = c2{(i==t)?1.f:0.f, 0.f};
#pragma unroll
      for (int l = 0; l < 2; ++l) {
        c2 M[16];
#pragma unroll
        for (int k = 0; k < 16; ++k) M[k] = SU[l][k];
        apply2q<8,4>(psi, M);
        apply2q<4,2>(psi, M);
        apply2q<2,1>(psi, M);
        apply2q<1,8>(psi, M);
      }
#pragma unroll
      for (int k = 0; k < 16; ++k) { Ur[k*17+t] = psi[k].x; Ui[k*17+t] = psi[k].y; }
    }
    __syncthreads();
    {
      int i = t >> 4, j = t & 15;
      float a0=0.f,a1=0.f,a2=0.f,a3=0.f;
#pragma unroll
      for (int k = 0; k < 16; ++k) {
        float pr = Ur[k*17+i]*Ur[k*17+j] + Ui[k*17+i]*Ui[k*17+j];
        a0 += ((k>>3)&1) ? -pr : pr;
        a1 += ((k>>2)&1) ? -pr : pr;
        a2 += ((k>>1)&1) ? -pr : pr;
        a3 += ( k     &1) ? -pr : pr;
      }
      A[0*256 + t] = a0; A[1*256 + t] = a1; A[2*256 + t] = a2; A[3*256 + t] = a3;
    }
    return;
  }
  int id = blockIdx.x*256 + t;
  if (id < 16384) { int j = id >> 6, o = id & 63;  wt[id] = w1a[o*256 + j]; return; }
  int id1 = id - 16384;
  if (id1 < 8192)  { int j = id1 >> 7, o = id1 & 127; wt[16384 + id1] = w1b[o*64 + j]; return; }
  int id2 = id1 - 8192;
  if (id2 < 8192)  { int j = id2 >> 6, o = id2 & 63;  wt[24576 + id2] = w2a[o*128 + j]; return; }
  int id3 = id2 - 8192;
  if (id3 < 640)   { int j = id3 / 10, o = id3 % 10;  wt[32768 + id3] = w2b[o*64 + j]; return; }
  int id4 = id3 - 640;
  if (id4 < 4608) {
    int s = id4 >> 8, rem = id4 & 255, l = rem >> 2, r = rem & 3;
    int tap = s >> 1, h = s & 1;
    int oc = l & 15, j = l >> 4;
    int icl = 16*h + 4*j + r;
    float lo = c2w[oc*576 + icl*9 + tap];
    float hi = c2w[oc*576 + (icl+32)*9 + tap];
    ((unsigned*)wt)[33408 + id4] = packh2(lo, hi);
    return;
  }
  int id5 = id4 - 4608;
  if (id5 < 1024) {
    int nt = id5 >> 8, rem = id5 & 255, l = rem >> 2, r = rem & 3;
    int oc = nt*16 + (l & 15), j = l >> 4;
    int k0 = 8*j + 2*r;
    float lo = (k0     < 27) ? c1w[oc*27 + k0]     : 0.f;
    float hi = (k0 + 1 < 27) ? c1w[oc*27 + k0 + 1] : 0.f;
    ((unsigned*)wt)[38016 + id5] = packh2(lo, hi);
  }
}

// ---- K12 v2: FUSED conv1+pool -> conv2+pool, direct A-frag build (no im2 buf). ----
// LDS = xs (13.9 KB) + hsp (46.7 KB) = 60.6 KB -> 2 blocks/CU (16 waves/CU).
// Per half h: lane builds its A-fragment (k-slice 8j..8j+7 of its position)
// straight from xs via 8 predicated reads + 4 packh2 (same RNE f16 values and
// k->j mapping as r16's im2col => bit-identical output). conv2 phase = v10.
__global__ __launch_bounds__(512, 2) void k_conv12(
    const float* __restrict__ x,
    const uint4* __restrict__ B1g, const float* __restrict__ b1,
    const uint4* __restrict__ B2g, const float* __restrict__ b2,
    float* __restrict__ h2) {
  __shared__ float xs[3480];           // [3][34][34] f32, stride 1156
  __shared__ unsigned hsp[11664];      // [18][18][36] u32
  int b = blockIdx.x, t = threadIdx.x;
  int l = t & 63, w = t >> 6;          // 8 waves
  int m = l & 15, j = l >> 4;
  // preload conv1 B-frags + bias
  uint4 Bf1[4];
#pragma unroll
  for (int nt = 0; nt < 4; ++nt) Bf1[nt] = B1g[nt*64 + l];
  float bz1[4];
#pragma unroll
  for (int nt = 0; nt < 4; ++nt) bz1[nt] = b1[nt*16 + m];
  // per-lane k-slice decode: kk = 8j+q -> (c, wr, cc), offset into xs
  int offs[8]; bool valid[8];
#pragma unroll
  for (int q = 0; q < 8; ++q) {
    int kk = 8*j + q;
    valid[q] = (kk < 27);
    int kc = valid[q] ? kk : 0;
    int c = kc / 9, rem = kc - 9*c, wr = rem / 3, cc = rem - 3*wr;
    offs[q] = c*1156 + wr*34 + cc;
  }
  // zero xs padding + hsp halo
  for (int i = t; i < 3480; i += 512) xs[i] = 0.f;
  {
    uint4 z = make_uint4(0u,0u,0u,0u);
    uint4* hz = (uint4*)hsp;
    for (int i = t; i < 2916; i += 512) hz[i] = z;
  }
  __syncthreads();
  // fill xs interior (coalesced)
  for (int i = t; i < 3072; i += 512) {
    int c = i >> 10, rem = i & 1023, gy = rem >> 5, gx = rem & 31;
    xs[c*1156 + (gy+1)*34 + gx + 1] = x[(size_t)b*3072 + i];
  }
  __syncthreads();
#pragma unroll
  for (int h = 0; h < 2; ++h) {
    f32x4v acc[2][2][4];               // [rr][xh][nt]
#pragma unroll
    for (int rr = 0; rr < 2; ++rr)
#pragma unroll
      for (int xh = 0; xh < 2; ++xh)
#pragma unroll
        for (int nt = 0; nt < 4; ++nt)
          acc[rr][xh][nt] = f32x4v{bz1[nt], bz1[nt], bz1[nt], bz1[nt]};
#pragma unroll
    for (int rr = 0; rr < 2; ++rr)
#pragma unroll
      for (int xh = 0; xh < 2; ++xh) {
        int base = (16*h + 2*w + rr)*34 + 16*xh + m;
        float v[8];
#pragma unroll
        for (int q = 0; q < 8; ++q) v[q] = valid[q] ? xs[offs[q] + base] : 0.f;
        unsigned a0 = packh2(v[0], v[1]), a1 = packh2(v[2], v[3]);
        unsigned a2u = packh2(v[4], v[5]), a3 = packh2(v[6], v[7]);
        uint4 Au = make_uint4(a0, a1, a2u, a3);
        f16x8 Av = __builtin_bit_cast(f16x8, Au);
#pragma unroll
        for (int nt = 0; nt < 4; ++nt)
          acc[rr][xh][nt] = __builtin_amdgcn_mfma_f32_16x16x32_f16(
              Av, __builtin_bit_cast(f16x8, Bf1[nt]), acc[rr][xh][nt], 0, 0, 0);
      }
    // pool 2x2 + relu + pack -> hsp (conv2 staging layout)
    {
      int pyg = 8*h + w;
#pragma unroll
      for (int ntp = 0; ntp < 2; ++ntp)
#pragma unroll
        for (int xh = 0; xh < 2; ++xh)
#pragma unroll
          for (int pv = 0; pv < 2; ++pv) {
            f32x4v aL0 = acc[0][xh][ntp],   aL1 = acc[1][xh][ntp];
            f32x4v aH0 = acc[0][xh][ntp+2], aH1 = acc[1][xh][ntp+2];
            float mlo = fmaxf(fmaxf(aL0[2*pv], aL0[2*pv+1]), fmaxf(aL1[2*pv], aL1[2*pv+1]));
            float mhi = fmaxf(fmaxf(aH0[2*pv], aH0[2*pv+1]), fmaxf(aH1[2*pv], aH1[2*pv+1]));
            int px = 8*xh + 2*j + pv;
            hsp[((pyg+1)*18 + px + 1)*36 + ntp*16 + m] =
                packh2(fmaxf(mlo, 0.f), fmaxf(mhi, 0.f));
          }
    }
  }
  __syncthreads();
  // --- conv2 phase (v10 layout, 8 waves x 2 row-tiles) ---
  uint4 Bf2[18];
#pragma unroll
  for (int s = 0; s < 18; ++s) Bf2[s] = B2g[s*64 + l];
  float bz2 = b2[m];
  f32x4v a2[2];
  a2[0] = f32x4v{bz2, bz2, bz2, bz2};
  a2[1] = f32x4v{bz2, bz2, bz2, bz2};
#pragma unroll
  for (int s = 0; s < 18; ++s) {
    const int tap = s >> 1, hh = s & 1;
    const int dy = tap / 3, dx = tap % 3;
    f16x8 Bv = __builtin_bit_cast(f16x8, Bf2[s]);
#pragma unroll
    for (int tt = 0; tt < 2; ++tt) {
      int y = 2*w + tt;
      f16x8 Av = __builtin_bit_cast(f16x8,
          *(const uint4*)(hsp + ((y+dy)*18 + m + dx)*36 + 16*hh + 4*j));
      a2[tt] = __builtin_amdgcn_mfma_f32_16x16x32_f16(Av, Bv, a2[tt], 0, 0, 0);
    }
  }
  float* outb = h2 + (size_t)b*1024 + m*64;
#pragma unroll
  for (int vp = 0; vp < 2; ++vp) {
    float mm = fmaxf(fmaxf(a2[0][2*vp], a2[0][2*vp+1]),
                     fmaxf(a2[1][2*vp], a2[1][2*vp+1]));
    outb[w*8 + 2*j + vp] = fmaxf(mm, 0.f);
  }
}

// ---- Ktail: conv3(16->4)+leaky+sigmoid*pi -> quantum forms -> full FC chain ----
__global__ __launch_bounds__(256) void k_tail(const float* __restrict__ h2, const float* __restrict__ w,
                                              const float* __restrict__ bias, const float* __restrict__ Ag,
                                              const float* __restrict__ wt,
                                              const float* __restrict__ b1a, const float* __restrict__ b1b,
                                              const float* __restrict__ b2a, const float* __restrict__ b2b,
                                              float* __restrict__ out) {
  __shared__ float S[8448];
  float* h3s = S;                      // [4][16][10][10] = 6400 (overlaid by fc S later)
  float* qs  = S + 6400;               // [4][256] = 1024
  float* As  = S + 7424;               // [4][256] = 1024
  int b4 = blockIdx.x*4, t = threadIdx.x;
#pragma unroll
  for (int k = 0; k < 4; ++k) As[t + k*256] = Ag[t + k*256];
  for (int i = t; i < 6400; i += 256) h3s[i] = 0.f;
  __syncthreads();
  int img = t >> 6, lane = t & 63;
  {
    const float4* src = (const float4*)(h2 + (size_t)(b4+img)*1024);
#pragma unroll
    for (int k = 0; k < 4; ++k) {
      float4 v = src[lane + k*64];
      int e = 4*(lane + k*64);
      int ic = e >> 6, iy = (e >> 3) & 7, ix = e & 7;
      float* d = &h3s[img*1600 + ic*100 + (iy+1)*10 + ix + 1];
      d[0]=v.x; d[1]=v.y; d[2]=v.z; d[3]=v.w;
    }
  }
  __syncthreads();
  {
    int y = lane >> 3, xo = lane & 7;
    float acc[4];
#pragma unroll
    for (int o = 0; o < 4; ++o) acc[o] = bias[o];
    for (int ic = 0; ic < 16; ++ic) {
      float in[3][3];
#pragma unroll
      for (int ky = 0; ky < 3; ++ky)
#pragma unroll
        for (int kx = 0; kx < 3; ++kx)
          in[ky][kx] = h3s[img*1600 + ic*100 + (y+ky)*10 + (xo+kx)];
#pragma unroll
      for (int o = 0; o < 4; ++o) {
        const float* wp = w + (o*16 + ic)*9;
#pragma unroll
        for (int ky = 0; ky < 3; ++ky)
#pragma unroll
          for (int kx = 0; kx < 3; ++kx)
            acc[o] = fmaf(wp[ky*3+kx], in[ky][kx], acc[o]);
      }
    }
    float v0[2], v1[2], v2[2], v3[2];
#pragma unroll
    for (int o = 0; o < 4; ++o) {
      float v = acc[o];
      float l = v > 0.f ? v : 0.01f*v;
      float sg = 1.f/(1.f + expf(-l));
      float sv, cv;
      __sincosf(sg * (0.5f*PI_F), &sv, &cv);
      float* dst = (o==0)?v0:(o==1)?v1:(o==2)?v2:v3;
      dst[0] = cv; dst[1] = sv;
    }
    float pv[16];
#pragma unroll
    for (int i = 0; i < 16; ++i)
      pv[i] = v0[(i>>3)&1] * v1[(i>>2)&1] * v2[(i>>1)&1] * v3[i&1];
#pragma unroll
    for (int w4 = 0; w4 < 4; ++w4) {
      const float4* Aw = (const float4*)(As + w4*256);
      float a = 0.f;
#pragma unroll
      for (int i = 0; i < 16; ++i) {
        float d = 0.f;
#pragma unroll
        for (int j4 = 0; j4 < 4; ++j4) {
          float4 av = Aw[i*4 + j4];
          d = fmaf(av.x, pv[j4*4+0], d);
          d = fmaf(av.y, pv[j4*4+1], d);
          d = fmaf(av.z, pv[j4*4+2], d);
          d = fmaf(av.w, pv[j4*4+3], d);
        }
        a = fmaf(pv[i], d, a);
      }
      qs[img*256 + lane*4 + w4] = a;
    }
  }
  __syncthreads();
  int wv = img;
  float* Sw = S + wv*512;
  ((float4*)Sw)[lane] = ((const float4*)(qs + wv*256))[lane];
  __syncthreads();
  const float* WT1a = wt;
  const float* WT1b = wt + 16384;
  const float* WT2a = wt + 24576;
  const float* WT2b = wt + 32768;
  float acc = b1a[lane];
  for (int j = 0; j < 256; ++j) acc = fmaf(WT1a[j*64+lane], Sw[j], acc);
  float hR = fmaxf(acc, 0.f);
  __syncthreads();
  Sw[256+lane] = hR;
  __syncthreads();
  float a0 = b1b[lane], a1 = b1b[64+lane];
  for (int j = 0; j < 64; ++j) {
    float sj = Sw[256+j];
    a0 = fmaf(WT1b[j*128+lane],    sj, a0);
    a1 = fmaf(WT1b[j*128+64+lane], sj, a1);
  }
  __syncthreads();
  Sw[320+lane] = a0; Sw[384+lane] = a1;
  __syncthreads();
  float c2a = b2a[lane];
  for (int j = 0; j < 128; ++j) c2a = fmaf(WT2a[j*64+lane], Sw[320+j], c2a);
  float h2v = fmaxf(c2a, 0.f);
  __syncthreads();
  Sw[448+lane] = h2v;
  __syncthreads();
  if (lane < 10) {
    float o = b2b[lane];
    for (int j = 0; j < 64; ++j) o = fmaf(WT2b[j*10+lane], Sw[448+j], o);
    out[(size_t)(b4+wv)*10 + lane] = o;
  }
}

extern "C" void kernel_launch(void* const* d_in, const int* in_sizes, int n_in,
                              void* d_out, int out_size, void* d_ws, size_t ws_size,
                              hipStream_t stream) {
  const float* x       = (const float*)d_in[0];
  const float* conv1_w = (const float*)d_in[1];
  const float* conv1_b = (const float*)d_in[2];
  const float* conv2_w = (const float*)d_in[3];
  const float* conv2_b = (const float*)d_in[4];
  const float* conv3_w = (const float*)d_in[5];
  const float* conv3_b = (const float*)d_in[6];
  const float* qw_u3   = (const float*)d_in[7];
  const float* qw_ang  = (const float*)d_in[8];
  const float* fc1a_w  = (const float*)d_in[9];
  const float* fc1a_b  = (const float*)d_in[10];
  const float* fc1b_w  = (const float*)d_in[11];
  const float* fc1b_b  = (const float*)d_in[12];
  const float* fc2a_w  = (const float*)d_in[13];
  const float* fc2a_b  = (const float*)d_in[14];
  const float* fc2b_w  = (const float*)d_in[15];
  const float* fc2b_b  = (const float*)d_in[16];
  float* out = (float*)d_out;

  float* ws  = (float*)d_ws;
  float* A   = ws;                      // 1024 floats
  float* WT  = ws + 1024;               // fc transposes (33408) + conv2 B (4608 u32) + conv1 B (1024 u32)
  const uint4* BG  = (const uint4*)((const unsigned*)WT + 33408);
  const uint4* B1G = (const uint4*)((const unsigned*)WT + 38016);
  float* h2  = ws + 17083008;           // 1048576 floats (1024x16x8x8)

  k_setup <<<168,  256, 0, stream>>>(fc1a_w, fc1b_w, fc2a_w, fc2b_w, conv2_w, conv1_w, conv1_b,
                                     qw_u3, qw_ang, WT, A);
  k_conv12<<<1024, 512, 0, stream>>>(x, B1G, conv1_b, BG, conv2_b, h2);
  k_tail  <<<256,  256, 0, stream>>>(h2, conv3_w, conv3_b, A, WT,
                                     fc1a_b, fc1b_b, fc2a_b, fc2b_b, out);
}

// Round 18
// 48.221 us; speedup vs baseline: 2.8654x; 1.2058x over previous
//
#include <hip/hip_runtime.h>
#include <math.h>

#define PI_F 3.14159265358979323846f

typedef _Float16 half2_t __attribute__((ext_vector_type(2)));
typedef _Float16 f16x8 __attribute__((ext_vector_type(8)));
typedef float f32x4v __attribute__((ext_vector_type(4)));

__device__ __forceinline__ unsigned packh2(float lo, float hi) {
  unsigned short l = __builtin_bit_cast(unsigned short, (_Float16)lo);
  unsigned short h = __builtin_bit_cast(unsigned short, (_Float16)hi);
  return (unsigned)l | ((unsigned)h << 16);
}

struct c2 { float x, y; };
__device__ __forceinline__ c2 cmul(c2 a, c2 b){ return c2{a.x*b.x - a.y*b.y, a.x*b.y + a.y*b.x}; }
__device__ __forceinline__ c2 cadd(c2 a, c2 b){ return c2{a.x+b.x, a.y+b.y}; }

__device__ __forceinline__ void rot2(c2 &a, c2 &b, c2 g00, c2 g01, c2 g10, c2 g11) {
  c2 na = cadd(cmul(g00,a), cmul(g01,b));
  c2 nb = cadd(cmul(g10,a), cmul(g11,b));
  a = na; b = nb;
}

__device__ __forceinline__ void mk_u3(float th, float ph, float la,
                                      c2 &g00, c2 &g01, c2 &g10, c2 &g11) {
  float ch = cosf(0.5f*th), sh = sinf(0.5f*th);
  float cl = cosf(la), sl = sinf(la);
  float cp = cosf(ph), sp = sinf(ph);
  float cpl = cp*cl - sp*sl, spl = sp*cl + cp*sl;
  g00 = c2{ch, 0.f};
  g01 = c2{-cl*sh, -sl*sh};
  g10 = c2{cp*sh, sp*sh};
  g11 = c2{cpl*ch, spl*ch};
}

template<int MA, int MB>
__device__ __forceinline__ void apply2q(c2 psi[16], const c2 M[16]) {
#pragma unroll
  for (int r = 0; r < 16; ++r) {
    if (r & (MA | MB)) continue;
    c2 a = psi[r], b = psi[r|MB], c = psi[r|MA], d = psi[r|MA|MB];
    psi[r]        = cadd(cadd(cmul(M[0],a),  cmul(M[1],b)),  cadd(cmul(M[2],c),  cmul(M[3],d)));
    psi[r|MB]     = cadd(cadd(cmul(M[4],a),  cmul(M[5],b)),  cadd(cmul(M[6],c),  cmul(M[7],d)));
    psi[r|MA]     = cadd(cadd(cmul(M[8],a),  cmul(M[9],b)),  cadd(cmul(M[10],c), cmul(M[11],d)));
    psi[r|MA|MB]  = cadd(cadd(cmul(M[12],a), cmul(M[13],b)), cadd(cmul(M[14],c), cmul(M[15],d)));
  }
}

// ------- Ksetup: blocks 0..166 = weight transposes/packs; block 167 = qmat. -------
__global__ __launch_bounds__(256) void k_setup(const float* __restrict__ w1a, const float* __restrict__ w1b,
                                               const float* __restrict__ w2a, const float* __restrict__ w2b,
                                               const float* __restrict__ c2w,
                                               const float* __restrict__ c1w, const float* __restrict__ c1b,
                                               const float* __restrict__ qw_u3,
                                               const float* __restrict__ qw_ang,
                                               float* __restrict__ wt, float* __restrict__ A) {
  __shared__ c2 SU[2][16];
  __shared__ float Ur[16*17], Ui[16*17];
  int t = threadIdx.x;
  if (blockIdx.x == 167) {
    if (t < 8) {
      int L = t >> 2, col = t & 3;
      c2 s[4];
#pragma unroll
      for (int i = 0; i < 4; ++i) s[i] = c2{(i==col)?1.f:0.f, 0.f};
      const float* u = qw_u3 + 12*L;
      const float* g = qw_ang + 3*L;
      c2 g00,g01,g10,g11;
      mk_u3(u[0],u[1],u[2], g00,g01,g10,g11);
      rot2(s[0],s[2], g00,g01,g10,g11); rot2(s[1],s[3], g00,g01,g10,g11);
      mk_u3(u[3],u[4],u[5], g00,g01,g10,g11);
      rot2(s[0],s[1], g00,g01,g10,g11); rot2(s[2],s[3], g00,g01,g10,g11);
      { c2 tmp = s[2]; s[2] = s[3]; s[3] = tmp; }
      { float c = cosf(0.5f*g[0]), sn = sinf(0.5f*g[0]);
        c2 r00{c,0.f}, r01{-sn,0.f}, r10{sn,0.f}, r11{c,0.f};
        rot2(s[0],s[2], r00,r01,r10,r11); rot2(s[1],s[3], r00,r01,r10,r11); }
      { float c = cosf(0.5f*g[1]), sn = sinf(0.5f*g[1]);
        c2 e0{c,-sn}, e1{c,sn};
        s[0]=cmul(s[0],e0); s[1]=cmul(s[1],e1); s[2]=cmul(s[2],e0); s[3]=cmul(s[3],e1); }
      { c2 tmp = s[1]; s[1] = s[3]; s[3] = tmp; }
      { float c = cosf(0.5f*g[2]), sn = sinf(0.5f*g[2]);
        c2 r00{c,0.f}, r01{-sn,0.f}, r10{sn,0.f}, r11{c,0.f};
        rot2(s[0],s[2], r00,r01,r10,r11); rot2(s[1],s[3], r00,r01,r10,r11); }
      { c2 tmp = s[2]; s[2] = s[3]; s[3] = tmp; }
      mk_u3(u[6],u[7],u[8], g00,g01,g10,g11);
      rot2(s[0],s[2], g00,g01,g10,g11); rot2(s[1],s[3], g00,g01,g10,g11);
      mk_u3(u[9],u[10],u[11], g00,g01,g10,g11);
      rot2(s[0],s[1], g00,g01,g10,g11); rot2(s[2],s[3], g00,g01,g10,g11);
#pragma unroll
      for (int k = 0; k < 4; ++k) SU[L][k*4 + col] = s[k];
    }
    __syncthreads();
    if (t < 16) {
      c2 psi[16];
#pragma unroll
      for (int i = 0; i < 16; ++i) psi[i] = c2{(i==t)?1.f:0.f, 0.f};
#pragma unroll
      for (int l = 0; l < 2; ++l) {
        c2 M[16];
#pragma unroll
        for (int k = 0; k < 16; ++k) M[k] = SU[l][k];
        apply2q<8,4>(psi, M);
        apply2q<4,2>(psi, M);
        apply2q<2,1>(psi, M);
        apply2q<1,8>(psi, M);
      }
#pragma unroll
      for (int k = 0; k < 16; ++k) { Ur[k*17+t] = psi[k].x; Ui[k*17+t] = psi[k].y; }
    }
    __syncthreads();
    {
      int i = t >> 4, j = t & 15;
      float a0=0.f,a1=0.f,a2=0.f,a3=0.f;
#pragma unroll
      for (int k = 0; k < 16; ++k) {
        float pr = Ur[k*17+i]*Ur[k*17+j] + Ui[k*17+i]*Ui[k*17+j];
        a0 += ((k>>3)&1) ? -pr : pr;
        a1 += ((k>>2)&1) ? -pr : pr;
        a2 += ((k>>1)&1) ? -pr : pr;
        a3 += ( k     &1) ? -pr : pr;
      }
      A[0*256 + t] = a0; A[1*256 + t] = a1; A[2*256 + t] = a2; A[3*256 + t] = a3;
    }
    return;
  }
  int id = blockIdx.x*256 + t;
  if (id < 16384) { int j = id >> 6, o = id & 63;  wt[id] = w1a[o*256 + j]; return; }
  int id1 = id - 16384;
  if (id1 < 8192)  { int j = id1 >> 7, o = id1 & 127; wt[16384 + id1] = w1b[o*64 + j]; return; }
  int id2 = id1 - 8192;
  if (id2 < 8192)  { int j = id2 >> 6, o = id2 & 63;  wt[24576 + id2] = w2a[o*128 + j]; return; }
  int id3 = id2 - 8192;
  if (id3 < 640)   { int j = id3 / 10, o = id3 % 10;  wt[32768 + id3] = w2b[o*64 + j]; return; }
  int id4 = id3 - 640;
  if (id4 < 4608) {
    int s = id4 >> 8, rem = id4 & 255, l = rem >> 2, r = rem & 3;
    int tap = s >> 1, h = s & 1;
    int oc = l & 15, j = l >> 4;
    int icl = 16*h + 4*j + r;
    float lo = c2w[oc*576 + icl*9 + tap];
    float hi = c2w[oc*576 + (icl+32)*9 + tap];
    ((unsigned*)wt)[33408 + id4] = packh2(lo, hi);
    return;
  }
  int id5 = id4 - 4608;
  if (id5 < 1024) {
    int nt = id5 >> 8, rem = id5 & 255, l = rem >> 2, r = rem & 3;
    int oc = nt*16 + (l & 15), j = l >> 4;
    int k0 = 8*j + 2*r;
    float lo = (k0     < 27) ? c1w[oc*27 + k0]     : 0.f;
    float hi = (k0 + 1 < 27) ? c1w[oc*27 + k0 + 1] : 0.f;
    ((unsigned*)wt)[38016 + id5] = packh2(lo, hi);
  }
}

// ---- K12 v2: FUSED conv1+pool -> conv2+pool (unchanged from r17, measured good). ----
__global__ __launch_bounds__(512, 2) void k_conv12(
    const float* __restrict__ x,
    const uint4* __restrict__ B1g, const float* __restrict__ b1,
    const uint4* __restrict__ B2g, const float* __restrict__ b2,
    float* __restrict__ h2) {
  __shared__ float xs[3480];           // [3][34][34] f32, stride 1156
  __shared__ unsigned hsp[11664];      // [18][18][36] u32
  int b = blockIdx.x, t = threadIdx.x;
  int l = t & 63, w = t >> 6;          // 8 waves
  int m = l & 15, j = l >> 4;
  uint4 Bf1[4];
#pragma unroll
  for (int nt = 0; nt < 4; ++nt) Bf1[nt] = B1g[nt*64 + l];
  float bz1[4];
#pragma unroll
  for (int nt = 0; nt < 4; ++nt) bz1[nt] = b1[nt*16 + m];
  int offs[8]; bool valid[8];
#pragma unroll
  for (int q = 0; q < 8; ++q) {
    int kk = 8*j + q;
    valid[q] = (kk < 27);
    int kc = valid[q] ? kk : 0;
    int c = kc / 9, rem = kc - 9*c, wr = rem / 3, cc = rem - 3*wr;
    offs[q] = c*1156 + wr*34 + cc;
  }
  for (int i = t; i < 3480; i += 512) xs[i] = 0.f;
  {
    uint4 z = make_uint4(0u,0u,0u,0u);
    uint4* hz = (uint4*)hsp;
    for (int i = t; i < 2916; i += 512) hz[i] = z;
  }
  __syncthreads();
  for (int i = t; i < 3072; i += 512) {
    int c = i >> 10, rem = i & 1023, gy = rem >> 5, gx = rem & 31;
    xs[c*1156 + (gy+1)*34 + gx + 1] = x[(size_t)b*3072 + i];
  }
  __syncthreads();
#pragma unroll
  for (int h = 0; h < 2; ++h) {
    f32x4v acc[2][2][4];               // [rr][xh][nt]
#pragma unroll
    for (int rr = 0; rr < 2; ++rr)
#pragma unroll
      for (int xh = 0; xh < 2; ++xh)
#pragma unroll
        for (int nt = 0; nt < 4; ++nt)
          acc[rr][xh][nt] = f32x4v{bz1[nt], bz1[nt], bz1[nt], bz1[nt]};
#pragma unroll
    for (int rr = 0; rr < 2; ++rr)
#pragma unroll
      for (int xh = 0; xh < 2; ++xh) {
        int base = (16*h + 2*w + rr)*34 + 16*xh + m;
        float v[8];
#pragma unroll
        for (int q = 0; q < 8; ++q) v[q] = valid[q] ? xs[offs[q] + base] : 0.f;
        unsigned a0 = packh2(v[0], v[1]), a1 = packh2(v[2], v[3]);
        unsigned a2u = packh2(v[4], v[5]), a3 = packh2(v[6], v[7]);
        uint4 Au = make_uint4(a0, a1, a2u, a3);
        f16x8 Av = __builtin_bit_cast(f16x8, Au);
#pragma unroll
        for (int nt = 0; nt < 4; ++nt)
          acc[rr][xh][nt] = __builtin_amdgcn_mfma_f32_16x16x32_f16(
              Av, __builtin_bit_cast(f16x8, Bf1[nt]), acc[rr][xh][nt], 0, 0, 0);
      }
    {
      int pyg = 8*h + w;
#pragma unroll
      for (int ntp = 0; ntp < 2; ++ntp)
#pragma unroll
        for (int xh = 0; xh < 2; ++xh)
#pragma unroll
          for (int pv = 0; pv < 2; ++pv) {
            f32x4v aL0 = acc[0][xh][ntp],   aL1 = acc[1][xh][ntp];
            f32x4v aH0 = acc[0][xh][ntp+2], aH1 = acc[1][xh][ntp+2];
            float mlo = fmaxf(fmaxf(aL0[2*pv], aL0[2*pv+1]), fmaxf(aL1[2*pv], aL1[2*pv+1]));
            float mhi = fmaxf(fmaxf(aH0[2*pv], aH0[2*pv+1]), fmaxf(aH1[2*pv], aH1[2*pv+1]));
            int px = 8*xh + 2*j + pv;
            hsp[((pyg+1)*18 + px + 1)*36 + ntp*16 + m] =
                packh2(fmaxf(mlo, 0.f), fmaxf(mhi, 0.f));
          }
    }
  }
  __syncthreads();
  uint4 Bf2[18];
#pragma unroll
  for (int s = 0; s < 18; ++s) Bf2[s] = B2g[s*64 + l];
  float bz2 = b2[m];
  f32x4v a2[2];
  a2[0] = f32x4v{bz2, bz2, bz2, bz2};
  a2[1] = f32x4v{bz2, bz2, bz2, bz2};
#pragma unroll
  for (int s = 0; s < 18; ++s) {
    const int tap = s >> 1, hh = s & 1;
    const int dy = tap / 3, dx = tap % 3;
    f16x8 Bv = __builtin_bit_cast(f16x8, Bf2[s]);
#pragma unroll
    for (int tt = 0; tt < 2; ++tt) {
      int y = 2*w + tt;
      f16x8 Av = __builtin_bit_cast(f16x8,
          *(const uint4*)(hsp + ((y+dy)*18 + m + dx)*36 + 16*hh + 4*j));
      a2[tt] = __builtin_amdgcn_mfma_f32_16x16x32_f16(Av, Bv, a2[tt], 0, 0, 0);
    }
  }
  float* outb = h2 + (size_t)b*1024 + m*64;
#pragma unroll
  for (int vp = 0; vp < 2; ++vp) {
    float mm = fmaxf(fmaxf(a2[0][2*vp], a2[0][2*vp+1]),
                     fmaxf(a2[1][2*vp], a2[1][2*vp+1]));
    outb[w*8 + 2*j + vp] = fmaxf(mm, 0.f);
  }
}

// ---- Ktail v2: one image per block (grid 1024, 4 blocks/CU), phase-parallel. ----
// conv3: thread=(oc,pos). quantum: thread=(patch,w4). fc1a/fc2a: 4-seg partial +
// tree reduce. fc1b: 128 threads full dot. fc2b: 10 threads.
__global__ __launch_bounds__(256) void k_tail(const float* __restrict__ h2, const float* __restrict__ w,
                                              const float* __restrict__ bias, const float* __restrict__ Ag,
                                              const float* __restrict__ wt,
                                              const float* __restrict__ b1a, const float* __restrict__ b1b,
                                              const float* __restrict__ b2a, const float* __restrict__ b2b,
                                              float* __restrict__ out) {
  __shared__ float h3s[1600];          // [16][10][10] zero-padded
  __shared__ float As[1024];           // [4][256]
  __shared__ float c3s[4][64];
  __shared__ float qs[256];
  __shared__ float red[256];
  __shared__ float h1s[64];
  __shared__ float hbv[128];
  __shared__ float h3v[64];
  int b = blockIdx.x, t = threadIdx.x;
#pragma unroll
  for (int k = 0; k < 4; ++k) As[t + ((k + (t>>6)) & 3)*256 - 0] = As[t + ((k + (t>>6)) & 3)*256 - 0]; // placeholder no-op removed below
  // (real loads)
#pragma unroll
  for (int k = 0; k < 4; ++k) As[k*256 + t] = Ag[k*256 + t];
  for (int i = t; i < 1600; i += 256) h3s[i] = 0.f;
  __syncthreads();
  {
    const float4* src = (const float4*)(h2 + (size_t)b*1024);
    float4 v = src[t];
    int e = 4*t;
    int ic = e >> 6, iy = (e >> 3) & 7, ix = e & 7;
    float* d = &h3s[ic*100 + (iy+1)*10 + ix + 1];
    d[0]=v.x; d[1]=v.y; d[2]=v.z; d[3]=v.w;
  }
  __syncthreads();
  // conv3: thread = (oc = t>>6, pos = t&63)
  {
    int oc = t >> 6, pos = t & 63;
    int y = pos >> 3, xo = pos & 7;
    float acc = bias[oc];
    const float* wp = w + oc*144;
    for (int ic = 0; ic < 16; ++ic) {
#pragma unroll
      for (int ky = 0; ky < 3; ++ky)
#pragma unroll
        for (int kx = 0; kx < 3; ++kx)
          acc = fmaf(wp[ic*9 + ky*3 + kx], h3s[ic*100 + (y+ky)*10 + (xo+kx)], acc);
    }
    c3s[oc][pos] = acc;
  }
  __syncthreads();
  // quantum: thread = (patch p = t&63, w4 = t>>6)
  {
    int p = t & 63, w4 = t >> 6;
    float v0[2], v1[2], v2[2], v3[2];
#pragma unroll
    for (int o = 0; o < 4; ++o) {
      float v = c3s[o][p];
      float lv = v > 0.f ? v : 0.01f*v;
      float sg = 1.f/(1.f + expf(-lv));
      float sv, cv;
      __sincosf(sg * (0.5f*PI_F), &sv, &cv);
      float* dst = (o==0)?v0:(o==1)?v1:(o==2)?v2:v3;
      dst[0] = cv; dst[1] = sv;
    }
    float pv[16];
#pragma unroll
    for (int i = 0; i < 16; ++i)
      pv[i] = v0[(i>>3)&1] * v1[(i>>2)&1] * v2[(i>>1)&1] * v3[i&1];
    const float4* Aw = (const float4*)(As + w4*256);
    float a = 0.f;
#pragma unroll
    for (int i = 0; i < 16; ++i) {
      float d = 0.f;
#pragma unroll
      for (int j4 = 0; j4 < 4; ++j4) {
        float4 av = Aw[i*4 + j4];
        d = fmaf(av.x, pv[j4*4+0], d);
        d = fmaf(av.y, pv[j4*4+1], d);
        d = fmaf(av.z, pv[j4*4+2], d);
        d = fmaf(av.w, pv[j4*4+3], d);
      }
      a = fmaf(pv[i], d, a);
    }
    qs[p*4 + w4] = a;
  }
  __syncthreads();
  const float* WT1a = wt;
  const float* WT1b = wt + 16384;
  const float* WT2a = wt + 24576;
  const float* WT2b = wt + 32768;
  // fc1a: 64 outputs x 256-dot, 4 segments of 64
  {
    int o = t & 63, seg = t >> 6;
    float acc = 0.f;
    const float* wp = WT1a + seg*64*64 + o;
    const float* qp = qs + seg*64;
    for (int jj = 0; jj < 64; ++jj) acc = fmaf(wp[jj*64], qp[jj], acc);
    red[seg*64 + o] = acc;
  }
  __syncthreads();
  if (t < 64) {
    float s = red[t] + red[64+t] + red[128+t] + red[192+t] + b1a[t];
    h1s[t] = fmaxf(s, 0.f);
  }
  __syncthreads();
  // fc1b: 128 outputs x 64-dot
  if (t < 128) {
    float acc = b1b[t];
    for (int j = 0; j < 64; ++j) acc = fmaf(WT1b[j*128 + t], h1s[j], acc);
    hbv[t] = acc;
  }
  __syncthreads();
  // fc2a: 64 outputs x 128-dot, 4 segments of 32
  {
    int o = t & 63, seg = t >> 6;
    float acc = 0.f;
    const float* wp = WT2a + seg*32*64 + o;
    const float* hp = hbv + seg*32;
    for (int jj = 0; jj < 32; ++jj) acc = fmaf(wp[jj*64], hp[jj], acc);
    red[seg*64 + o] = acc;
  }
  __syncthreads();
  if (t < 64) {
    float s = red[t] + red[64+t] + red[128+t] + red[192+t] + b2a[t];
    h3v[t] = fmaxf(s, 0.f);
  }
  __syncthreads();
  // fc2b: 10 outputs x 64-dot
  if (t < 10) {
    float o = b2b[t];
    for (int j = 0; j < 64; ++j) o = fmaf(WT2b[j*10 + t], h3v[j], o);
    out[(size_t)b*10 + t] = o;
  }
}

extern "C" void kernel_launch(void* const* d_in, const int* in_sizes, int n_in,
                              void* d_out, int out_size, void* d_ws, size_t ws_size,
                              hipStream_t stream) {
  const float* x       = (const float*)d_in[0];
  const float* conv1_w = (const float*)d_in[1];
  const float* conv1_b = (const float*)d_in[2];
  const float* conv2_w = (const float*)d_in[3];
  const float* conv2_b = (const float*)d_in[4];
  const float* conv3_w = (const float*)d_in[5];
  const float* conv3_b = (const float*)d_in[6];
  const float* qw_u3   = (const float*)d_in[7];
  const float* qw_ang  = (const float*)d_in[8];
  const float* fc1a_w  = (const float*)d_in[9];
  const float* fc1a_b  = (const float*)d_in[10];
  const float* fc1b_w  = (const float*)d_in[11];
  const float* fc1b_b  = (const float*)d_in[12];
  const float* fc2a_w  = (const float*)d_in[13];
  const float* fc2a_b  = (const float*)d_in[14];
  const float* fc2b_w  = (const float*)d_in[15];
  const float* fc2b_b  = (const float*)d_in[16];
  float* out = (float*)d_out;

  float* ws  = (float*)d_ws;
  float* A   = ws;                      // 1024 floats
  float* WT  = ws + 1024;               // fc transposes (33408) + conv2 B (4608 u32) + conv1 B (1024 u32)
  const uint4* BG  = (const uint4*)((const unsigned*)WT + 33408);
  const uint4* B1G = (const uint4*)((const unsigned*)WT + 38016);
  float* h2  = ws + 17083008;           // 1048576 floats (1024x16x8x8)

  k_setup <<<168,  256, 0, stream>>>(fc1a_w, fc1b_w, fc2a_w, fc2b_w, conv2_w, conv1_w, conv1_b,
                                     qw_u3, qw_ang, WT, A);
  k_conv12<<<1024, 512, 0, stream>>>(x, B1G, conv1_b, BG, conv2_b, h2);
  k_tail  <<<1024, 256, 0, stream>>>(h2, conv3_w, conv3_b, A, WT,
                                     fc1a_b, fc1b_b, fc2a_b, fc2b_b, out);
}